// Round 8
// baseline (2284.722 us; speedup 1.0000x reference)
//
#include <hip/hip_runtime.h>
#include <hip/hip_bf16.h>
#include <math.h>

typedef __hip_bfloat16 bf16;
typedef short v8s __attribute__((ext_vector_type(8)));
typedef float v4f __attribute__((ext_vector_type(4)));

#define NB   1024
#define NT   128
#define NH   128
#define HE   256
#define HD   132
#define HDP  160
#define HDS  164
#define GDP  144
#define NS   8
#define KX   32
#define RG   16          // batch rows per encoder row-group
#define NRG  64          // row groups (64*16 = 1024)

namespace wsoff {
constexpr size_t al(size_t x){ return (x + 255) & ~size_t(255); }
constexpr size_t FLAG  = 0;
constexpr size_t CNT   = 256;                  // 192 counters x 64B
constexpr size_t XS    = al(CNT + 192*64);
constexpr size_t MASKT = al(XS    + (size_t)NT*NB*KX*2);   // int32 [NT][NB]
constexpr size_t WIH0  = al(MASKT + (size_t)NT*NB*4);
constexpr size_t WHH0  = al(WIH0  + 768*32*2);
constexpr size_t WIH1  = al(WHH0  + 768*256*2);
constexpr size_t WHH1  = al(WIH1  + 768*256*2);
constexpr size_t BIH0  = al(WHH1  + 768*256*2);
constexpr size_t BHH0  = al(BIH0  + 768*4);
constexpr size_t BIH1  = al(BHH0  + 768*4);
constexpr size_t BHH1  = al(BIH1  + 768*4);
constexpr size_t WDHH0 = al(BHH1  + 768*4);
constexpr size_t WDIH1 = al(WDHH0 + 432*HDP*2);
constexpr size_t WDHH1 = al(WDIH1 + 432*HDP*2);
constexpr size_t WDIH0F= al(WDHH1 + 432*HDP*2);
constexpr size_t BDIH0 = al(WDIH0F+ 792*4);
constexpr size_t BDHH0 = al(BDIH0 + 396*4);
constexpr size_t BDIH1 = al(BDHH0 + 396*4);
constexpr size_t BDHH1 = al(BDIH1 + 396*4);
constexpr size_t W1B   = al(BDHH1 + 396*4);
constexpr size_t B1F   = al(W1B   + 64*128*2);
constexpr size_t W2F   = al(B1F   + 64*4);
constexpr size_t B2F   = al(W2F   + 128*4);
constexpr size_t H0F0  = al(B2F   + 2*4);
constexpr size_t H1F0  = al(H0F0  + (size_t)NB*HE*4);
constexpr size_t RING0 = al(H1F0  + (size_t)NB*HE*4);          // 64 grp x 4 slot x 16x256 bf16
constexpr size_t RING1 = al(RING0 + (size_t)NRG*4*RG*256*2);   // 128 blk x 2 slot x 16x128 bf16
constexpr size_t ENCP  = al(RING1 + (size_t)128*2*RG*128*2);
}

// ---------- helpers ----------
__device__ __forceinline__ float ld_any(const void* p, size_t i, int isbf){
  return isbf ? __bfloat162float(((const bf16*)p)[i]) : ((const float*)p)[i];
}
__device__ __forceinline__ void st_out(void* out, size_t i, float v, int isbf){
  if (isbf) ((bf16*)out)[i] = __float2bfloat16(v); else ((float*)out)[i] = v;
}
__device__ __forceinline__ float sigm(float x){ return 1.0f/(1.0f + __expf(-x)); }
__device__ __forceinline__ float tanh_f(float x){
  float t = __expf(2.0f*x); return 1.0f - 2.0f/(t+1.0f);
}
__device__ __forceinline__ float softplusf(float x){ return x>20.f ? x : log1pf(__expf(x)); }
__device__ __forceinline__ v4f mfma16(v8s a, v8s b, v4f c){
  return __builtin_amdgcn_mfma_f32_16x16x32_bf16(a,b,c,0,0,0);
}
__device__ __forceinline__ v8s fragld(const bf16* base, size_t elem_off){
  return *reinterpret_cast<const v8s*>(base + elem_off);
}
__device__ __forceinline__ v8s ldsfrag(const short* sm, int unit, int lane){
  return *reinterpret_cast<const v8s*>(sm + (unit<<9) + (lane<<3));
}
__device__ __forceinline__ v8s lds_frag8(const short* p){
  union { long long l[2]; v8s s; } r;
  r.l[0] = *(const long long*)(p);
  r.l[1] = *(const long long*)(p + 4);
  return r.s;
}
__device__ __forceinline__ short bf16bits(float v){
  bf16 h = __float2bfloat16(v); short s; __builtin_memcpy(&s,&h,2); return s;
}
__device__ __forceinline__ float uasf(unsigned u){ float f; __builtin_memcpy(&f,&u,4); return f; }
__device__ __forceinline__ v8s ldg_coh16(const bf16* p){
  union { unsigned long long u[2]; v8s s; } r;
  const unsigned long long* q = (const unsigned long long*)p;
  r.u[0] = __hip_atomic_load(q+0, __ATOMIC_RELAXED, __HIP_MEMORY_SCOPE_AGENT);
  r.u[1] = __hip_atomic_load(q+1, __ATOMIC_RELAXED, __HIP_MEMORY_SCOPE_AGENT);
  return r.s;
}
__device__ __forceinline__ void stg_coh_pair(bf16* base_even, int lr, float v){
  bf16 h = __float2bfloat16(v);
  unsigned vv; { unsigned short b; __builtin_memcpy(&b, &h, 2); vv = b; }
  unsigned ov = (unsigned)__shfl_xor((int)vv, 1, 64);
  if (!(lr & 1))
    __hip_atomic_store((unsigned*)base_even, vv | (ov<<16), __ATOMIC_RELAXED, __HIP_MEMORY_SCOPE_AGENT);
}
__device__ __forceinline__ float*  f32p(char* ws, size_t off){ return (float*)(ws+off); }
__device__ __forceinline__ bf16*   bfp (char* ws, size_t off){ return (bf16*)(ws+off); }

// ---------- counters ----------
__device__ __forceinline__ int* cntp(char* ws, int idx){
  return (int*)(ws + wsoff::CNT + (size_t)idx*64);
}
__device__ __forceinline__ void pollge(int* f, int v){
  while (__hip_atomic_load(f, __ATOMIC_RELAXED, __HIP_MEMORY_SCOPE_AGENT) < v)
    __builtin_amdgcn_s_sleep(1);
}
__device__ __forceinline__ void cntset(int* f, int v){
  __hip_atomic_store(f, v, __ATOMIC_RELAXED, __HIP_MEMORY_SCOPE_AGENT);
}

// ---------- dtype detection ----------
__global__ void k_detect(char* ws, const void* eps){
  const unsigned short* p = (const unsigned short*)eps;
  int lane = threadIdx.x;
  unsigned short u = p[2*lane];
  int e = (u>>7)&0xFF;
  bool pl = (e>=118 && e<=130);
  unsigned long long m = __ballot(pl);
  if (lane==0) *(int*)(ws+wsoff::FLAG) = (__popcll(m) >= 32) ? 1 : 0;
}

// ---------- staging ----------
__global__ void k_stage_xs(char* ws, const void* x, const void* feat){
  int isbf = *(const int*)(ws+wsoff::FLAG);
  size_t i = (size_t)blockIdx.x*blockDim.x + threadIdx.x;
  if (i >= (size_t)NT*NB*KX) return;
  int c = i % KX; size_t q = i / KX; int b = q % NB; int t = q / NB;
  float v = 0.f;
  if (c < 2)        v = ld_any(x,    ((size_t)b*NT + t)*2 + c, isbf);
  else if (c < 18)  v = ld_any(feat, ((size_t)b*192 + t)*16 + (c-2), isbf);
  ((bf16*)(ws+wsoff::XS))[i] = __float2bfloat16(v);
}
__global__ void k_stage_maskT(char* ws, const int* mask){
  size_t i = (size_t)blockIdx.x*blockDim.x + threadIdx.x;
  if (i >= (size_t)NT*NB) return;
  int b = i % NB, t = i / NB;
  ((int*)(ws+wsoff::MASKT))[i] = mask[(size_t)b*NT + t];
}
__global__ void k_stage_pad(char* ws, const void* src, size_t dstoff, int R, int SC, int DC){
  int isbf = *(const int*)(ws+wsoff::FLAG);
  size_t i = (size_t)blockIdx.x*blockDim.x + threadIdx.x;
  if (i >= (size_t)R*DC) return;
  int r = i / DC, c = i % DC;
  float v = (c < SC) ? ld_any(src, (size_t)r*SC + c, isbf) : 0.f;
  ((bf16*)(ws+dstoff))[i] = __float2bfloat16(v);
}
__global__ void k_stage_dec(char* ws, const void* src, size_t dstoff){
  int isbf = *(const int*)(ws+wsoff::FLAG);
  size_t i = (size_t)blockIdx.x*blockDim.x + threadIdx.x;
  if (i >= (size_t)432*HDP) return;
  int R = i / HDP, c = i % HDP;
  int g = R / GDP, ii = R % GDP;
  float v = (ii < HD && c < HD) ? ld_any(src, ((size_t)(g*HD+ii))*HD + c, isbf) : 0.f;
  ((bf16*)(ws+dstoff))[i] = __float2bfloat16(v);
}
struct SmallSegs { const void* src[12]; int dstoff[12]; int n[12]; };
__global__ void k_stage_small(char* ws, SmallSegs segs){
  int isbf = *(const int*)(ws+wsoff::FLAG);
  int s = blockIdx.x;
  float* dst = (float*)(ws + (size_t)segs.dstoff[s]);
  for (int i = threadIdx.x; i < segs.n[s]; i += blockDim.x)
    dst[i] = ld_any(segs.src[s], i, isbf);
}

// ================= persistent encoder: row-ownership, weights resident per CU =================
#define ENC_LDS 156928
__global__ __attribute__((amdgpu_flat_work_group_size(512,512), amdgpu_waves_per_eu(1)))
void k_encoder(char* ws){
  extern __shared__ __align__(16) char smem[];
  const int bid = blockIdx.x, tid = threadIdx.x;
  const int lane = tid & 63, w = tid >> 6, lr = lane & 15, q = lane >> 4;
  const int* maskT = (const int*)(ws + wsoff::MASKT);

  if (bid < NRG){
    // ---------------- LAYER 0 ----------------
    constexpr int NL0 = 18;              // LDS weight tiles per wave (of 54)
    constexpr int NR0 = 54 - NL0;        // 36 register tiles (144 VGPR)
    const int rb = bid, rowbase = rb*RG;
    short* wlds = (short*)smem;                     // 8*18 KB
    short* abuf = (short*)(smem + 8*NL0*1024);      // [16][296] bf16: k = 256 h | 32 x | 8 pad
    int* cL0 = cntp(ws, rb);
    int* cXa = cntp(ws, NRG + rb*2);
    int* cXb = cntp(ws, NRG + rb*2 + 1);
    const short* WH = (const short*)(ws + wsoff::WHH0);
    const short* WI = (const short*)(ws + wsoff::WIH0);
    for (int idx = tid; idx < 8*NL0*512; idx += 512){
      int slot = idx >> 9, le = idx & 511, ln = le >> 3, j = le & 7, lrr = ln & 15, qq = ln >> 4;
      int w2 = slot / NL0, i = slot % NL0;
      int kb = i % 9, t2 = i / 9, g = t2 % 3, cs = t2 / 3;
      int row = g*HE + w2*32 + cs*16 + lrr;
      wlds[idx] = (kb < 8) ? WH[(size_t)row*256 + kb*32 + qq*8 + j]
                           : WI[(size_t)row*32  + qq*8 + j];
    }
    for (int idx = tid; idx < RG*296; idx += 512) abuf[idx] = 0;
    v8s wreg[NR0];
    #pragma unroll
    for (int i = NL0; i < 54; ++i){
      int kb = i % 9, t2 = i / 9, g = t2 % 3, cs = t2 / 3;
      int row = g*HE + w*32 + cs*16 + lr;
      wreg[i-NL0] = (kb < 8) ? fragld(bfp(ws,wsoff::WHH0), (size_t)row*256 + kb*32 + q*8)
                             : fragld(bfp(ws,wsoff::WIH0), (size_t)row*32 + q*8);
    }
    const float* bih = f32p(ws,wsoff::BIH0);
    const float* bhh = f32p(ws,wsoff::BHH0);
    float birv[2], bizv[2], binv[2], bhnv[2];
    #pragma unroll
    for (int cs=0;cs<2;cs++){
      int d = w*32 + cs*16 + lr;
      birv[cs]=bih[d]+bhh[d]; bizv[cs]=bih[HE+d]+bhh[HE+d];
      binv[cs]=bih[2*HE+d];   bhnv[cs]=bhh[2*HE+d];
    }
    float h0a[2][4] = {};
    float* hTf = f32p(ws, wsoff::H0F0);
    bf16* ring0 = bfp(ws, wsoff::RING0) + (size_t)rb*4*RG*256;
    const bf16* Xs = bfp(ws,wsoff::XS);
    __syncthreads();
    for (int t = 0; t < 128; ++t){
      if (tid == 0 && t >= 4){          // ring0 depth 4 back-pressure
        pollge(cXa, t-3); pollge(cXb, t-3);
      }
      __syncthreads();                  // S1
      if (tid < 64){                    // stage x[t] into abuf k 256..287
        int row = tid >> 2, ck = tid & 3;
        v8s xv = fragld(Xs, ((size_t)t*NB + rowbase + row)*KX + ck*8);
        *(v8s*)(abuf + row*296 + 256 + ck*8) = xv;
      }
      __syncthreads();                  // S2
      v4f accr[2], accz[2], accxn[2], acchn[2];
      #pragma unroll
      for (int cs=0;cs<2;cs++){
        accr[cs]=(v4f){0,0,0,0}; accz[cs]=(v4f){0,0,0,0};
        accxn[cs]=(v4f){0,0,0,0}; acchn[cs]=(v4f){0,0,0,0};
      }
      #pragma unroll
      for (int kb=0;kb<9;kb++){
        v8s af = lds_frag8(abuf + lr*296 + kb*32 + q*8);
        #pragma unroll
        for (int cs=0;cs<2;cs++)
          #pragma unroll
          for (int g=0;g<3;g++){
            int i = (cs*3+g)*9 + kb;
            v8s b = (i < NL0) ? ldsfrag(wlds, w*NL0 + i, lane) : wreg[i-NL0];
            v4f* A = (g==0)?&accr[cs]:(g==1)?&accz[cs]:((kb<8)?&acchn[cs]:&accxn[cs]);
            *A = mfma16(af, b, *A);
          }
      }
      int mk[4];
      #pragma unroll
      for (int rr=0;rr<4;rr++) mk[rr] = maskT[(size_t)t*NB + rowbase + q*4 + rr];
      __syncthreads();                  // S3: all A reads done -> safe to overwrite h
      bf16* slot = ring0 + (size_t)(t&3)*RG*256;
      #pragma unroll
      for (int cs=0;cs<2;cs++){
        int d = w*32 + cs*16 + lr;
        #pragma unroll
        for (int rr=0;rr<4;rr++){
          int row = q*4 + rr;
          float rg = sigm(accr[cs][rr] + birv[cs]);
          float zg = sigm(accz[cs][rr] + bizv[cs]);
          float nn = tanh_f(accxn[cs][rr] + binv[cs] + rg*(acchn[cs][rr]+bhnv[cs]));
          float hv = (1.f-zg)*nn + zg*h0a[cs][rr];
          float h2 = mk[rr] ? hv : h0a[cs][rr];
          h0a[cs][rr] = h2;
          abuf[row*296 + d] = bf16bits(h2);
          stg_coh_pair(slot + ((size_t)row*256 + (d & ~1)), lr, h2);
          if (t == 127) hTf[(size_t)(rowbase+row)*HE + d] = h2;
        }
      }
      __syncthreads();                  // S4: ring stores drained (vmcnt0 per thread)
      if (tid == 0) cntset(cL0, t+1);
    }
  } else {
    // ---------------- LAYER 1 (+ fused MLP on col-half 0) ----------------
    constexpr int NL1 = 15;              // LDS weight tiles per wave (of 48)
    constexpr int NR1 = 48 - NL1;        // 33 register tiles (132 VGPR)
    const int id = bid - NRG, rb = id >> 1, ch = id & 1;
    const int rowbase = rb*RG;
    short* wlds = (short*)smem;                                 // 8*15 KB
    short* abuf = (short*)(smem + 8*NL1*1024);                  // [16][520]: k = 256 h0 | 256 h1 | 8 pad
    short* w1s  = (short*)(smem + 8*NL1*1024 + RG*520*2);       // MLP W1 tiles, 16KB (ch0 only)
    int* cL0 = cntp(ws, rb);
    int* cXo = cntp(ws, NRG + rb*2 + ch);
    int* cXp = cntp(ws, NRG + rb*2 + (ch^1));
    const short* WX = (const short*)(ws + wsoff::WIH1);
    const short* WHs= (const short*)(ws + wsoff::WHH1);
    for (int idx = tid; idx < 8*NL1*512; idx += 512){
      int slot = idx >> 9, le = idx & 511, ln = le >> 3, j = le & 7, lrr = ln & 15, qq = ln >> 4;
      int w2 = slot / NL1, i = slot % NL1;
      int kb = i & 15, g = i >> 4;
      int row = g*HE + ch*128 + w2*16 + lrr;
      wlds[idx] = (kb < 8) ? WX [(size_t)row*256 + kb*32 + qq*8 + j]
                           : WHs[(size_t)row*256 + (kb-8)*32 + qq*8 + j];
    }
    if (ch == 0){
      const short* W1s = (const short*)(ws + wsoff::W1B);
      for (int idx = tid; idx < 16*512; idx += 512){
        int u = idx >> 9, le = idx & 511, ln = le >> 3, j = le & 7, lrr = ln & 15, qq = ln >> 4;
        int c = u >> 2, kb = u & 3;
        w1s[idx] = W1s[(size_t)(c*16 + lrr)*NH + kb*32 + qq*8 + j];
      }
    }
    for (int idx = tid; idx < RG*520; idx += 512) abuf[idx] = 0;
    v8s wreg[NR1];
    #pragma unroll
    for (int i = NL1; i < 48; ++i){
      int kb = i & 15, g = i >> 4;
      int row = g*HE + ch*128 + w*16 + lr;
      wreg[i-NL1] = (kb < 8) ? fragld(bfp(ws,wsoff::WIH1), (size_t)row*256 + kb*32 + q*8)
                             : fragld(bfp(ws,wsoff::WHH1), (size_t)row*256 + (kb-8)*32 + q*8);
    }
    const float* bih = f32p(ws,wsoff::BIH1);
    const float* bhh = f32p(ws,wsoff::BHH1);
    const int d = ch*128 + w*16 + lr;
    const float birv=bih[d]+bhh[d], bizv=bih[HE+d]+bhh[HE+d];
    const float binv=bih[2*HE+d],   bhnv=bhh[2*HE+d];
    float h1a[4] = {};
    float b1v[4], w20[4], w21[4];
    #pragma unroll
    for (int c=0;c<4;c++){
      int col=c*16+lr;
      b1v[c]=f32p(ws,wsoff::B1F)[col];
      w20[c]=f32p(ws,wsoff::W2F)[col]; w21[c]=f32p(ws,wsoff::W2F)[64+col];
    }
    const float b20 = f32p(ws,wsoff::B2F)[0], b21 = f32p(ws,wsoff::B2F)[1];
    float* hTf = f32p(ws, wsoff::H1F0);
    const bf16* ring0 = bfp(ws, wsoff::RING0) + (size_t)rb*4*RG*256;
    bf16* ring1o       = bfp(ws, wsoff::RING1) + (size_t)id*2*RG*128;
    const bf16* ring1p = bfp(ws, wsoff::RING1) + (size_t)(id^1)*2*RG*128;
    float* encp = f32p(ws,wsoff::ENCP);
    __syncthreads();
    for (int s = 0; s < 128; ++s){
      if (tid == 0){
        pollge(cL0, s+1);                 // h0[s] published
        if (s >= 1) pollge(cXp, s);       // partner finished s-1 -> its h1 half published
      }
      __syncthreads();                    // S1
      {                                   // stage h0[s] (16x256) into abuf k 0..255
        const bf16* hs = ring0 + (size_t)(s&3)*RG*256;
        int row = tid >> 5, ck = tid & 31;
        v8s v = ldg_coh16(hs + (size_t)row*256 + ck*8);
        *(v8s*)(abuf + row*520 + ck*8) = v;
      }
      if (s >= 1 && tid < 256){           // stage partner h1 half (16x128)
        const bf16* hp = ring1p + (size_t)((s-1)&1)*RG*128;
        int row = tid >> 4, ck = tid & 15;
        v8s v = ldg_coh16(hp + (size_t)row*128 + ck*8);
        *(v8s*)(abuf + row*520 + 256 + (ch^1)*128 + ck*8) = v;
      }
      __syncthreads();                    // S2
      v4f accr=(v4f){0,0,0,0}, accz=(v4f){0,0,0,0};
      v4f accxn=(v4f){0,0,0,0}, acchn=(v4f){0,0,0,0};
      #pragma unroll
      for (int kb=0;kb<16;kb++){
        v8s af = lds_frag8(abuf + lr*520 + kb*32 + q*8);
        #pragma unroll
        for (int g=0;g<3;g++){
          int i = g*16 + kb;
          v8s b = (i < NL1) ? ldsfrag(wlds, w*NL1 + i, lane) : wreg[i-NL1];
          v4f* A = (g==0)?&accr:(g==1)?&accz:((kb<8)?&accxn:&acchn);
          *A = mfma16(af, b, *A);
        }
      }
      int mk[4];
      #pragma unroll
      for (int rr=0;rr<4;rr++) mk[rr] = maskT[(size_t)s*NB + rowbase + q*4 + rr];
      __syncthreads();                    // S3
      bf16* slot = ring1o + (size_t)(s&1)*RG*128;
      #pragma unroll
      for (int rr=0;rr<4;rr++){
        int row = q*4 + rr;
        float rg = sigm(accr[rr] + birv);
        float zg = sigm(accz[rr] + bizv);
        float nn = tanh_f(accxn[rr] + binv + rg*(acchn[rr]+bhnv));
        float hv = (1.f-zg)*nn + zg*h1a[rr];
        float h2 = mk[rr] ? hv : h1a[rr];
        h1a[rr] = h2;
        int ch_col = w*16 + lr;
        abuf[row*520 + 256 + ch*128 + ch_col] = bf16bits(h2);
        stg_coh_pair(slot + ((size_t)row*128 + (ch_col & ~1)), lr, h2);
        if (s == 127) hTf[(size_t)(rowbase+row)*HE + d] = h2;
      }
      __syncthreads();                    // S4: h1 stores drained
      if (tid == 0) cntset(cXo, s+1);
      // ---- fused MLP (needs h1[:, :128] = ch0's own half, already in abuf) ----
      if (ch == 0 && w == 0){
        int vl = maskT[(size_t)s*NB + rowbase + lr];
        v4f acc[4];
        #pragma unroll
        for (int c=0;c<4;c++) acc[c]=(v4f){0,0,0,0};
        #pragma unroll
        for (int kb=0;kb<4;kb++){
          v8s af = vl ? lds_frag8(abuf + lr*520 + 256 + kb*32 + q*8)
                      : (v8s){0,0,0,0,0,0,0,0};
          #pragma unroll
          for (int c=0;c<4;c++) acc[c] = mfma16(af, ldsfrag(w1s, c*4+kb, lane), acc[c]);
        }
        float* outp = encp + (size_t)s*NB*2;
        #pragma unroll
        for (int rr=0;rr<4;rr++){
          float p0=0.f, p1=0.f;
          #pragma unroll
          for (int c=0;c<4;c++){
            float hv = acc[c][rr] + b1v[c]; hv = hv>0.f ? hv : 0.f;
            p0 += hv*w20[c]; p1 += hv*w21[c];
          }
          #pragma unroll
          for (int m=1;m<16;m<<=1){ p0 += __shfl_xor(p0,m,64); p1 += __shfl_xor(p1,m,64); }
          if (lr == 0){
            int grow = rowbase + q*4 + rr;
            outp[(size_t)grow*2]   = softplusf(p0+b20);
            outp[(size_t)grow*2+1] = softplusf(p1+b21);
          }
        }
      }
    }
  }
}

// ================= decoder: 5-phase schedule =================
// Phases per iter: A=P1 epi (w7 finishes tail via shfl) | B=P2 MFMA (+w7 tail) |
// C=P2 epi (w7 tail via shfl) | D=MLP(w5,6)->s_red then ALL: next-iter P1 MFMA | E=P4 (tid<64).
// p1/pt computed in D, consumed in A of the next iter (live across E only - MLP block has them dead).
// s_tail buffer eliminated; tail epilogues run concurrently with main epilogues on wave 7.
#define DEC_LDS 163296
__global__ __attribute__((amdgpu_flat_work_group_size(512,512), amdgpu_waves_per_eu(1)))
void k_decoder(char* ws, const void* eps, const void* feat, void* out){
  extern __shared__ __align__(16) char dsm[];
  short* s_h0b = (short*)dsm;                       // [32][HDS]      @0      10496
  short* s_h1b = s_h0b + 32*HDS;                    //                @10496  10496
  float* s_inp = (float*)(dsm + 20992);             // [64]           @20992  256
  float* s_red = (float*)(dsm + 21248);             // [128]          @21248  512
  short* s_wh  = (short*)(dsm + 21760);             // WH1 t0..7 frag @21760  122880
  short* s_ct  = (short*)(dsm + 144640);            // [3][5][512] tail tiles  15360
  float* s_th  = (float*)(dsm + 162048);            // [2][32][4]             1024
  float* s_tt0 = (float*)(dsm + 163072);            // [4][10]                160
  float* s_tt1 = (float*)(dsm + 163232);            // [4][4]                 64

  const int isbf = *(const int*)(ws+wsoff::FLAG);
  const int tid = threadIdx.x;
  const int lane = tid & 63, w = tid >> 6, lr = lane & 15, q = lane >> 4;
  const int rowbase = blockIdx.x*32;
  constexpr size_t N0v = (size_t)NS*NB*127*2;

  const bf16* W0g  = bfp(ws,wsoff::WDHH0);
  const bf16* WX1g = bfp(ws,wsoff::WDIH1);

  // ---- phase A0: zero + LDS staging ----
  for (int i = tid; i < 2*32*HDS; i += 512) s_h0b[i] = 0;
  {
    const short* src = (const short*)(ws + wsoff::WDHH1);
    for (int idx = tid; idx < 120*512; idx += 512){
      int u = idx >> 9, le = idx & 511, ln = le >> 3, e = le & 7, lrr = ln & 15, qq = ln >> 4;
      int kb = u % 5, t2 = u / 5, cc = t2 & 7, g = t2 >> 3;
      s_wh[idx] = src[(size_t)(g*GDP + cc*16 + lrr)*HDP + kb*32 + qq*8 + e];
    }
  }
  // composite tail tiles: set1 cols 0..3=r,4..7=z,8..11=xn(P1: h-dots of WDHH0);
  // set2 (x) same cols; set3 (h) cols 0..7=r,z and 12..15=hn. P2 sums set2+set3 in one acc.
  {
    const short* g0 = (const short*)(ws + wsoff::WDHH0);
    const short* gx = (const short*)(ws + wsoff::WDIH1);
    const short* gh = (const short*)(ws + wsoff::WDHH1);
    for (int idx = tid; idx < 5*512; idx += 512){
      int kb = idx >> 9, le = idx & 511, l = le >> 3, j = le & 7, lrr = l & 15, qq = l >> 4;
      short v0 = 0, vx = 0, vh = 0;
      if (lrr < 12){
        int g = lrr >> 2, cc = lrr & 3;
        size_t so = (size_t)(g*GDP + 128 + cc)*HDP + kb*32 + qq*8 + j;
        v0 = g0[so]; vx = gx[so];
        if (lrr < 8) vh = gh[so];
      } else {
        int cc = lrr & 3;
        size_t so = (size_t)(2*GDP + 128 + cc)*HDP + kb*32 + qq*8 + j;
        vh = gh[so];
      }
      s_ct[idx]          = v0;
      s_ct[5*512 + idx]  = vx;
      s_ct[10*512 + idx] = vh;
    }
  }
  if (tid < 4){
    const float* wih = f32p(ws,wsoff::WDIH0F);
    const float* bi0 = f32p(ws,wsoff::BDIH0); const float* bh0 = f32p(ws,wsoff::BDHH0);
    const float* bi1 = f32p(ws,wsoff::BDIH1); const float* bh1 = f32p(ws,wsoff::BDHH1);
    int dd = 128 + tid;
    float* T = s_tt0 + tid*10;
    T[0]=wih[(0*HD+dd)*2]; T[1]=wih[(0*HD+dd)*2+1];
    T[2]=wih[(1*HD+dd)*2]; T[3]=wih[(1*HD+dd)*2+1];
    T[4]=wih[(2*HD+dd)*2]; T[5]=wih[(2*HD+dd)*2+1];
    T[6]=bi0[dd]+bh0[dd]; T[7]=bi0[HD+dd]+bh0[HD+dd]; T[8]=bi0[2*HD+dd]; T[9]=bh0[2*HD+dd];
    float* T1 = s_tt1 + tid*4;
    T1[0]=bi1[dd]+bh1[dd]; T1[1]=bi1[HD+dd]+bh1[HD+dd]; T1[2]=bi1[2*HD+dd]; T1[3]=bh1[2*HD+dd];
  }
  if (tid < 64){
    int r0 = tid >> 1, c = tid & 1;
    int b = (rowbase + r0) & 1023;
    float v = f32p(ws,wsoff::ENCP)[((size_t)127*NB + b)*2 + c];
    s_inp[tid] = v;
    st_out(out, N0v + ((size_t)(rowbase+r0)*64)*2 + c, v, isbf);
  }
  __syncthreads();

  // ---- phase B0: per-thread state init + RF weights ----
  const int d = w*16 + lr;   // always < 128
  float e0a[10], e1a[4];
  {
    const float* wih = f32p(ws,wsoff::WDIH0F);
    const float* bi0 = f32p(ws,wsoff::BDIH0); const float* bh0 = f32p(ws,wsoff::BDHH0);
    const float* bi1 = f32p(ws,wsoff::BDIH1); const float* bh1 = f32p(ws,wsoff::BDHH1);
    e0a[0]=wih[(0*HD+d)*2]; e0a[1]=wih[(0*HD+d)*2+1];
    e0a[2]=wih[(1*HD+d)*2]; e0a[3]=wih[(1*HD+d)*2+1];
    e0a[4]=wih[(2*HD+d)*2]; e0a[5]=wih[(2*HD+d)*2+1];
    e0a[6]=bi0[d]+bh0[d]; e0a[7]=bi0[HD+d]+bh0[HD+d]; e0a[8]=bi0[2*HD+d]; e0a[9]=bh0[2*HD+d];
    e1a[0]=bi1[d]+bh1[d]; e1a[1]=bi1[HD+d]+bh1[HD+d]; e1a[2]=bi1[2*HD+d]; e1a[3]=bh1[2*HD+d];
  }
  float h0a[2][4], h1a[2][4];
  {
    const float* h0T = f32p(ws,wsoff::H0F0);
    const float* h1T = f32p(ws,wsoff::H1F0);
    #pragma unroll
    for (int m=0;m<2;m++)
      #pragma unroll
      for (int r=0;r<4;r++){
        int row = m*16 + q*4 + r, grow = rowbase + row;
        int s = grow >> 10, b = grow & 1023;
        float e0 = ld_any(eps, ((size_t)(s*2+0)*NB + b)*NH + d, isbf);
        float e1 = ld_any(eps, ((size_t)(s*2+1)*NB + b)*NH + d, isbf);
        float v0 = e0*__expf(0.5f*h0T[(size_t)b*HE + NH + d]) + h0T[(size_t)b*HE + d];
        float v1 = e1*__expf(0.5f*h1T[(size_t)b*HE + NH + d]) + h1T[(size_t)b*HE + d];
        h0a[m][r] = v0; h1a[m][r] = v1;
        s_h0b[row*HDS + d] = bf16bits(v0);
        s_h1b[row*HDS + d] = bf16bits(v1);
      }
  }
  if (tid < 128){
    int c4i = tid >> 5, row = tid & 31;
    int b = (rowbase + row) & 1023;
    float fc = ld_any(feat, (size_t)b*3072 + 2048 + c4i, isbf);
    s_th[row*4 + c4i] = fc;
    s_th[128 + row*4 + c4i] = fc;
    s_h0b[row*HDS + 128 + c4i] = bf16bits(fc);
    s_h1b[row*HDS + 128 + c4i] = bf16bits(fc);
  }
  v8s w0f[3][5], wxf[3][5];
  #pragma unroll
  for (int g=0;g<3;g++)
    #pragma unroll
    for (int kb=0;kb<5;kb++){
      size_t off = (size_t)(g*GDP + w*16 + lr)*HDP + kb*32 + q*8;
      w0f[g][kb] = fragld(W0g, off);
      wxf[g][kb] = fragld(WX1g, off);
    }
  const float b20 = f32p(ws,wsoff::B2F)[0], b21 = f32p(ws,wsoff::B2F)[1];
  __syncthreads();

  const int tc4 = lane & 3;
  v4f p1[3][2]; v4f pt[2];
  auto run_p1 = [&](){
    #pragma unroll
    for (int g=0;g<3;g++){ p1[g][0]=(v4f){0,0,0,0}; p1[g][1]=(v4f){0,0,0,0}; }
    pt[0]=(v4f){0,0,0,0}; pt[1]=(v4f){0,0,0,0};
    #pragma unroll
    for (int m=0;m<2;m++)
      #pragma unroll
      for (int kb=0;kb<5;kb++){
        v8s A = lds_frag8(s_h0b + (m*16+lr)*HDS + kb*32 + q*8);
        #pragma unroll
        for (int g=0;g<3;g++) p1[g][m] = mfma16(A, w0f[g][kb], p1[g][m]);
        if (w == 7) pt[m] = mfma16(A, ldsfrag(s_ct, kb, lane), pt[m]);
      }
  };
  run_p1();   // prologue: P1 MFMA for step 0 (reads initialized s_h0b)

  for (int k = 0; k < 63; ++k){
    __syncthreads();                       // B0: s_inp(k) ready; all waves hold p1
    // ---- Phase A: P1 epilogue (all waves) + wave-7 tail epilogue via shfl ----
    #pragma unroll
    for (int m=0;m<2;m++)
      #pragma unroll
      for (int r=0;r<4;r++){
        int row = m*16 + q*4 + r;
        float i0 = s_inp[row*2], i1 = s_inp[row*2+1];
        float rr = sigm(i0*e0a[0]+i1*e0a[1] + p1[0][m][r] + e0a[6]);
        float zz = sigm(i0*e0a[2]+i1*e0a[3] + p1[1][m][r] + e0a[7]);
        float nn = tanh_f(i0*e0a[4]+i1*e0a[5] + e0a[8] + rr*(p1[2][m][r] + e0a[9]));
        float h = (1.f-zz)*nn + zz*h0a[m][r];
        h0a[m][r] = h;
        s_h0b[row*HDS + d] = bf16bits(h);
      }
    if (w == 7){
      #pragma unroll
      for (int m=0;m<2;m++)
        #pragma unroll
        for (int r=0;r<4;r++){
          float ar = __shfl(pt[m][r], (lane & 48) | tc4, 64);
          float az = __shfl(pt[m][r], (lane & 48) | (4+tc4), 64);
          float an = __shfl(pt[m][r], (lane & 48) | (8+tc4), 64);
          if (lr < 4){
            int row = m*16 + q*4 + r;
            const float* T = s_tt0 + tc4*10;
            float i0 = s_inp[row*2], i1 = s_inp[row*2+1];
            float rg = sigm(i0*T[0]+i1*T[1] + ar + T[6]);
            float zg = sigm(i0*T[2]+i1*T[3] + az + T[7]);
            float nn = tanh_f(i0*T[4]+i1*T[5] + T[8] + rg*(an + T[9]));
            float ho = s_th[row*4 + tc4];
            float h = (1.f-zg)*nn + zg*ho;
            s_th[row*4 + tc4] = h;
            s_h0b[row*HDS + 128 + tc4] = bf16bits(h);
          }
        }
    }
    __syncthreads();                       // B1: s_h0b new complete
    // ---- Phase B: P2 MFMA (+w7 single-acc tail) ----
    v4f p2[4][2]; v4f pt2[2];
    #pragma unroll
    for (int g=0;g<4;g++){ p2[g][0]=(v4f){0,0,0,0}; p2[g][1]=(v4f){0,0,0,0}; }
    pt2[0]=(v4f){0,0,0,0}; pt2[1]=(v4f){0,0,0,0};
    #pragma unroll
    for (int m=0;m<2;m++)
      #pragma unroll
      for (int kb=0;kb<5;kb++){
        v8s ax = lds_frag8(s_h0b + (m*16+lr)*HDS + kb*32 + q*8);
        v8s ah = lds_frag8(s_h1b + (m*16+lr)*HDS + kb*32 + q*8);
        #pragma unroll
        for (int g=0;g<3;g++){
          int aix = (g==2) ? 2 : g, aih = (g==2) ? 3 : g;
          p2[aix][m] = mfma16(ax, wxf[g][kb], p2[aix][m]);
          p2[aih][m] = mfma16(ah, ldsfrag(s_wh, (g*8+w)*5 + kb, lane), p2[aih][m]);
        }
        if (w == 7){
          pt2[m] = mfma16(ax, ldsfrag(s_ct, 5 + kb, lane), pt2[m]);
          pt2[m] = mfma16(ah, ldsfrag(s_ct, 10 + kb, lane), pt2[m]);
        }
      }
    __syncthreads();                       // B2: all P2 reads of s_h1b(old) done
    // ---- Phase C: P2 epilogue (all waves) + wave-7 tail epilogue via shfl ----
    #pragma unroll
    for (int m=0;m<2;m++)
      #pragma unroll
      for (int r=0;r<4;r++){
        int row = m*16 + q*4 + r;
        float rr = sigm(p2[0][m][r] + e1a[0]);
        float zz = sigm(p2[1][m][r] + e1a[1]);
        float nn = tanh_f(p2[2][m][r] + e1a[2] + rr*(p2[3][m][r] + e1a[3]));
        float h = (1.f-zz)*nn + zz*h1a[m][r];
        h1a[m][r] = h;
        s_h1b[row*HDS + d] = bf16bits(h);
      }
    if (w == 7){
      #pragma unroll
      for (int m=0;m<2;m++)
        #pragma unroll
        for (int r=0;r<4;r++){
          float tr  = __shfl(pt2[m][r], (lane & 48) | tc4, 64);
          float tz  = __shfl(pt2[m][r], (lane & 48) | (4+tc4), 64);
          float txn = __shfl(pt2[m][r], (lane & 48) | (8+tc4), 64);
          float thn = __shfl(pt2[m][r], (lane & 48) | (12+tc4), 64);
          if (lr < 4){
            int row = m*16 + q*4 + r;
            const float* T1 = s_tt1 + tc4*4;
            float rg = sigm(tr + T1[0]);
            float zg = sigm(tz + T1[1]);
            float nn = tanh_f(txn + T1[2] + rg*(thn + T1[3]));
            float ho = s_th[128 + row*4 + tc4];
            float h = (1.f-zg)*nn + zg*ho;
            s_th[128 + row*4 + tc4] = h;
            s_h1b[row*HDS + 128 + tc4] = bf16bits(h);
          }
        }
    }
    __syncthreads();                       // B3: s_h1b new complete
    // ---- Phase D: MLP (w5,6) -> s_red, then ALL waves: next-iter P1 MFMA ----
    if (w == 5 || w == 6){
      const int tb = (w-5)*2;
      const bf16* W1g = bfp(ws,wsoff::W1B);
      v8s w1a[2][4];
      float b1vv[2], w20vv[2], w21vv[2];
      #pragma unroll
      for (int ct=0;ct<2;ct++){
        #pragma unroll
        for (int kb=0;kb<4;kb++)
          w1a[ct][kb] = fragld(W1g, (size_t)((tb+ct)*16+lr)*NH + kb*32 + q*8);
        b1vv[ct]  = f32p(ws,wsoff::B1F)[(tb+ct)*16+lr];
        w20vv[ct] = f32p(ws,wsoff::W2F)[(tb+ct)*16+lr];
        w21vv[ct] = f32p(ws,wsoff::W2F)[64+(tb+ct)*16+lr];
      }
      v4f a3[2][2];
      #pragma unroll
      for (int ct=0;ct<2;ct++){ a3[ct][0]=(v4f){0,0,0,0}; a3[ct][1]=(v4f){0,0,0,0}; }
      #pragma unroll
      for (int m=0;m<2;m++)
        #pragma unroll
        for (int kb=0;kb<4;kb++){
          v8s A = lds_frag8(s_h1b + (m*16+lr)*HDS + kb*32 + q*8);
          #pragma unroll
          for (int ct=0;ct<2;ct++) a3[ct][m] = mfma16(A, w1a[ct][kb], a3[ct][m]);
        }
      #pragma unroll
      for (int m=0;m<2;m++)
        #pragma unroll
        for (int r=0;r<4;r++){
          float p0 = 0.f, p1v = 0.f;
          #pragma unroll
          for (int ct=0;ct<2;ct++){
            float hv = a3[ct][m][r] + b1vv[ct]; hv = hv > 0.f ? hv : 0.f;
            p0 += hv*w20vv[ct]; p1v += hv*w21vv[ct];
          }
          #pragma unroll
          for (int mm=1;mm<16;mm<<=1){ p0 += __shfl_xor(p0,mm,64); p1v += __shfl_xor(p1v,mm,64); }
          if (lr == 0){
            int row = m*16 + q*4 + r;
            s_red[(w-5)*64 + row*2]   = p0;
            s_red[(w-5)*64 + row*2+1] = p1v;
          }
        }
    }
    run_p1();                              // next-iter P1 MFMA (reads stable s_h0b)
    __syncthreads();                       // B4: s_red ready
    // ---- Phase E: P4 combine + feedback + out ----
    if (tid < 64){
      int row = tid >> 1, c = tid & 1;
      float p = s_red[row*2 + c] + s_red[64 + row*2 + c];
      float v = softplusf(p + (c ? b21 : b20));
      s_inp[tid] = v;
      st_out(out, N0v + ((size_t)(rowbase+row)*64 + (k+1))*2 + c, v, isbf);
    }
  }
}

// ---------- encoder-part output assembly ----------
__global__ void k_assemble_enc(char* ws, void* out){
  int isbf = *(const int*)(ws+wsoff::FLAG);
  const float* encp = f32p(ws,wsoff::ENCP);
  constexpr size_t N0v = (size_t)NS*NB*127*2;
  for (size_t i = (size_t)blockIdx.x*blockDim.x + threadIdx.x; i < N0v;
       i += (size_t)gridDim.x*blockDim.x){
    int c = (int)(i & 1); size_t qq = i >> 1;
    int tt = (int)(qq % 127); size_t q2 = qq / 127; int b = (int)(q2 & 1023);
    st_out(out, i, encp[((size_t)tt*NB + b)*2 + c], isbf);
  }
}

extern "C" void kernel_launch(void* const* d_in, const int* in_sizes, int n_in,
                              void* d_out, int out_size, void* d_ws, size_t ws_size,
                              hipStream_t stream) {
  char* ws = (char*)d_ws;
  const int* mask = (const int*)d_in[2];
  auto gb = [](size_t n){ return dim3((unsigned)((n + 255)/256)); };

  hipMemsetAsync(ws+wsoff::CNT, 0, 192*64, stream);

  k_detect<<<1,64,0,stream>>>(ws, d_in[3]);

  k_stage_xs   <<<gb((size_t)NT*NB*KX),256,0,stream>>>(ws, d_in[0], d_in[1]);
  k_stage_maskT<<<gb((size_t)NT*NB),256,0,stream>>>(ws, mask);
  k_stage_pad<<<gb(768*32) ,256,0,stream>>>(ws, d_in[7],  wsoff::WIH0, 768, 18, 32);
  k_stage_pad<<<gb(768*256),256,0,stream>>>(ws, d_in[8],  wsoff::WHH0, 768, 256, 256);
  k_stage_pad<<<gb(768*256),256,0,stream>>>(ws, d_in[11], wsoff::WIH1, 768, 256, 256);
  k_stage_pad<<<gb(768*256),256,0,stream>>>(ws, d_in[12], wsoff::WHH1, 768, 256, 256);
  k_stage_pad<<<gb(64*128) ,256,0,stream>>>(ws, d_in[23], wsoff::W1B,  64, 128, 128);
  k_stage_dec<<<gb(432*HDP),256,0,stream>>>(ws, d_in[16], wsoff::WDHH0);
  k_stage_dec<<<gb(432*HDP),256,0,stream>>>(ws, d_in[19], wsoff::WDIH1);
  k_stage_dec<<<gb(432*HDP),256,0,stream>>>(ws, d_in[20], wsoff::WDHH1);

  SmallSegs ss;
  const void* srcs[12] = {d_in[9],d_in[10],d_in[13],d_in[14],d_in[15],
                          d_in[17],d_in[18],d_in[21],d_in[22],
                          d_in[24],d_in[25],d_in[26]};
  const size_t offs[12] = {wsoff::BIH0,wsoff::BHH0,wsoff::BIH1,wsoff::BHH1,wsoff::WDIH0F,
                           wsoff::BDIH0,wsoff::BDHH0,wsoff::BDIH1,wsoff::BDHH1,
                           wsoff::B1F,wsoff::W2F,wsoff::B2F};
  const int ns[12] = {768,768,768,768,792,396,396,396,396,64,128,2};
  for (int i=0;i<12;i++){ ss.src[i]=srcs[i]; ss.dstoff[i]=(int)offs[i]; ss.n[i]=ns[i]; }
  k_stage_small<<<12,256,0,stream>>>(ws, ss);

  hipFuncSetAttribute(reinterpret_cast<const void*>(k_encoder),
                      hipFuncAttributeMaxDynamicSharedMemorySize, ENC_LDS);
  hipFuncSetAttribute(reinterpret_cast<const void*>(k_decoder),
                      hipFuncAttributeMaxDynamicSharedMemorySize, DEC_LDS);

  k_encoder<<<192,512,ENC_LDS,stream>>>(ws);
  k_decoder<<<256,512,DEC_LDS,stream>>>(ws, d_in[3], d_in[1], d_out);
  k_assemble_enc<<<2048,256,0,stream>>>(ws, d_out);
}

// Round 9
// 1866.844 us; speedup vs baseline: 1.2238x; 1.2238x over previous
//
#include <hip/hip_runtime.h>
#include <hip/hip_bf16.h>
#include <math.h>

typedef __hip_bfloat16 bf16;
typedef short v8s __attribute__((ext_vector_type(8)));
typedef float v4f __attribute__((ext_vector_type(4)));

#define NB   1024
#define NT   128
#define NH   128
#define HE   256
#define HD   132
#define HDP  160
#define HDS  164
#define GDP  144
#define NS   8
#define KX   32
#define RG   16          // batch rows per encoder row-group
#define NRG  64          // row groups (64*16 = 1024)

namespace wsoff {
constexpr size_t al(size_t x){ return (x + 255) & ~size_t(255); }
constexpr size_t FLAG  = 0;
constexpr size_t CNT   = 256;                  // 192 counters x 64B
constexpr size_t XS    = al(CNT + 192*64);
constexpr size_t MASKT = al(XS    + (size_t)NT*NB*KX*2);   // int32 [NT][NB]
constexpr size_t WIH0  = al(MASKT + (size_t)NT*NB*4);
constexpr size_t WHH0  = al(WIH0  + 768*32*2);
constexpr size_t WIH1  = al(WHH0  + 768*256*2);
constexpr size_t WHH1  = al(WIH1  + 768*256*2);
constexpr size_t BIH0  = al(WHH1  + 768*256*2);
constexpr size_t BHH0  = al(BIH0  + 768*4);
constexpr size_t BIH1  = al(BHH0  + 768*4);
constexpr size_t BHH1  = al(BIH1  + 768*4);
constexpr size_t WDHH0 = al(BHH1  + 768*4);
constexpr size_t WDIH1 = al(WDHH0 + 432*HDP*2);
constexpr size_t WDHH1 = al(WDIH1 + 432*HDP*2);
constexpr size_t WDIH0F= al(WDHH1 + 432*HDP*2);
constexpr size_t BDIH0 = al(WDIH0F+ 792*4);
constexpr size_t BDHH0 = al(BDIH0 + 396*4);
constexpr size_t BDIH1 = al(BDHH0 + 396*4);
constexpr size_t BDHH1 = al(BDIH1 + 396*4);
constexpr size_t W1B   = al(BDHH1 + 396*4);
constexpr size_t B1F   = al(W1B   + 64*128*2);
constexpr size_t W2F   = al(B1F   + 64*4);
constexpr size_t B2F   = al(W2F   + 128*4);
constexpr size_t H0F0  = al(B2F   + 2*4);
constexpr size_t H1F0  = al(H0F0  + (size_t)NB*HE*4);
constexpr size_t RING0 = al(H1F0  + (size_t)NB*HE*4);          // 64 grp x 4 slot x 16x256 bf16
constexpr size_t RING1 = al(RING0 + (size_t)NRG*4*RG*256*2);   // 128 slots (rb*2+ch) x 2 x 16x128 bf16
constexpr size_t ENCP  = al(RING1 + (size_t)128*2*RG*128*2);
}

// ---------- helpers ----------
__device__ __forceinline__ float ld_any(const void* p, size_t i, int isbf){
  return isbf ? __bfloat162float(((const bf16*)p)[i]) : ((const float*)p)[i];
}
__device__ __forceinline__ void st_out(void* out, size_t i, float v, int isbf){
  if (isbf) ((bf16*)out)[i] = __float2bfloat16(v); else ((float*)out)[i] = v;
}
__device__ __forceinline__ float sigm(float x){ return 1.0f/(1.0f + __expf(-x)); }
__device__ __forceinline__ float tanh_f(float x){
  float t = __expf(2.0f*x); return 1.0f - 2.0f/(t+1.0f);
}
__device__ __forceinline__ float softplusf(float x){ return x>20.f ? x : log1pf(__expf(x)); }
__device__ __forceinline__ v4f mfma16(v8s a, v8s b, v4f c){
  return __builtin_amdgcn_mfma_f32_16x16x32_bf16(a,b,c,0,0,0);
}
__device__ __forceinline__ v8s fragld(const bf16* base, size_t elem_off){
  return *reinterpret_cast<const v8s*>(base + elem_off);
}
__device__ __forceinline__ v8s ldsfrag(const short* sm, int unit, int lane){
  return *reinterpret_cast<const v8s*>(sm + (unit<<9) + (lane<<3));
}
__device__ __forceinline__ v8s lds_frag8(const short* p){
  union { long long l[2]; v8s s; } r;
  r.l[0] = *(const long long*)(p);
  r.l[1] = *(const long long*)(p + 4);
  return r.s;
}
__device__ __forceinline__ short bf16bits(float v){
  bf16 h = __float2bfloat16(v); short s; __builtin_memcpy(&s,&h,2); return s;
}
__device__ __forceinline__ float uasf(unsigned u){ float f; __builtin_memcpy(&f,&u,4); return f; }
__device__ __forceinline__ v8s ldg_coh16(const bf16* p){
  union { unsigned long long u[2]; v8s s; } r;
  const unsigned long long* q = (const unsigned long long*)p;
  r.u[0] = __hip_atomic_load(q+0, __ATOMIC_RELAXED, __HIP_MEMORY_SCOPE_AGENT);
  r.u[1] = __hip_atomic_load(q+1, __ATOMIC_RELAXED, __HIP_MEMORY_SCOPE_AGENT);
  return r.s;
}
__device__ __forceinline__ void stg_coh_pair(bf16* base_even, int lr, float v){
  bf16 h = __float2bfloat16(v);
  unsigned vv; { unsigned short b; __builtin_memcpy(&b, &h, 2); vv = b; }
  unsigned ov = (unsigned)__shfl_xor((int)vv, 1, 64);
  if (!(lr & 1))
    __hip_atomic_store((unsigned*)base_even, vv | (ov<<16), __ATOMIC_RELAXED, __HIP_MEMORY_SCOPE_AGENT);
}
__device__ __forceinline__ float*  f32p(char* ws, size_t off){ return (float*)(ws+off); }
__device__ __forceinline__ bf16*   bfp (char* ws, size_t off){ return (bf16*)(ws+off); }

// ---------- counters ----------
__device__ __forceinline__ int* cntp(char* ws, int idx){
  return (int*)(ws + wsoff::CNT + (size_t)idx*64);
}
__device__ __forceinline__ void pollge(int* f, int v){
  while (__hip_atomic_load(f, __ATOMIC_RELAXED, __HIP_MEMORY_SCOPE_AGENT) < v)
    __builtin_amdgcn_s_sleep(1);
}
__device__ __forceinline__ void cntset(int* f, int v){
  __hip_atomic_store(f, v, __ATOMIC_RELAXED, __HIP_MEMORY_SCOPE_AGENT);
}

// ---------- dtype detection ----------
__global__ void k_detect(char* ws, const void* eps){
  const unsigned short* p = (const unsigned short*)eps;
  int lane = threadIdx.x;
  unsigned short u = p[2*lane];
  int e = (u>>7)&0xFF;
  bool pl = (e>=118 && e<=130);
  unsigned long long m = __ballot(pl);
  if (lane==0) *(int*)(ws+wsoff::FLAG) = (__popcll(m) >= 32) ? 1 : 0;
}

// ---------- staging ----------
__global__ void k_stage_xs(char* ws, const void* x, const void* feat){
  int isbf = *(const int*)(ws+wsoff::FLAG);
  size_t i = (size_t)blockIdx.x*blockDim.x + threadIdx.x;
  if (i >= (size_t)NT*NB*KX) return;
  int c = i % KX; size_t q = i / KX; int b = q % NB; int t = q / NB;
  float v = 0.f;
  if (c < 2)        v = ld_any(x,    ((size_t)b*NT + t)*2 + c, isbf);
  else if (c < 18)  v = ld_any(feat, ((size_t)b*192 + t)*16 + (c-2), isbf);
  ((bf16*)(ws+wsoff::XS))[i] = __float2bfloat16(v);
}
__global__ void k_stage_maskT(char* ws, const int* mask){
  size_t i = (size_t)blockIdx.x*blockDim.x + threadIdx.x;
  if (i >= (size_t)NT*NB) return;
  int b = i % NB, t = i / NB;
  ((int*)(ws+wsoff::MASKT))[i] = mask[(size_t)b*NT + t];
}
__global__ void k_stage_pad(char* ws, const void* src, size_t dstoff, int R, int SC, int DC){
  int isbf = *(const int*)(ws+wsoff::FLAG);
  size_t i = (size_t)blockIdx.x*blockDim.x + threadIdx.x;
  if (i >= (size_t)R*DC) return;
  int r = i / DC, c = i % DC;
  float v = (c < SC) ? ld_any(src, (size_t)r*SC + c, isbf) : 0.f;
  ((bf16*)(ws+dstoff))[i] = __float2bfloat16(v);
}
__global__ void k_stage_dec(char* ws, const void* src, size_t dstoff){
  int isbf = *(const int*)(ws+wsoff::FLAG);
  size_t i = (size_t)blockIdx.x*blockDim.x + threadIdx.x;
  if (i >= (size_t)432*HDP) return;
  int R = i / HDP, c = i % HDP;
  int g = R / GDP, ii = R % GDP;
  float v = (ii < HD && c < HD) ? ld_any(src, ((size_t)(g*HD+ii))*HD + c, isbf) : 0.f;
  ((bf16*)(ws+dstoff))[i] = __float2bfloat16(v);
}
struct SmallSegs { const void* src[12]; int dstoff[12]; int n[12]; };
__global__ void k_stage_small(char* ws, SmallSegs segs){
  int isbf = *(const int*)(ws+wsoff::FLAG);
  int s = blockIdx.x;
  float* dst = (float*)(ws + (size_t)segs.dstoff[s]);
  for (int i = threadIdx.x; i < segs.n[s]; i += blockDim.x)
    dst[i] = ld_any(segs.src[s], i, isbf);
}

// ================= persistent encoder: row-ownership, weights resident per CU =================
// L1 partner pairing is XCD-aware: partner blocks differ by 8 in blockIdx, so under round-robin
// dispatch (XCD = bid % 8) the per-step 4KB h1-half exchange stays within one XCD's L2.
#define ENC_LDS 156928
__global__ __attribute__((amdgpu_flat_work_group_size(512,512), amdgpu_waves_per_eu(1)))
void k_encoder(char* ws){
  extern __shared__ __align__(16) char smem[];
  const int bid = blockIdx.x, tid = threadIdx.x;
  const int lane = tid & 63, w = tid >> 6, lr = lane & 15, q = lane >> 4;
  const int* maskT = (const int*)(ws + wsoff::MASKT);

  if (bid < NRG){
    // ---------------- LAYER 0 ----------------
    constexpr int NL0 = 18;              // LDS weight tiles per wave (of 54)
    constexpr int NR0 = 54 - NL0;        // 36 register tiles (144 VGPR)
    const int rb = bid, rowbase = rb*RG;
    short* wlds = (short*)smem;                     // 8*18 KB
    short* abuf = (short*)(smem + 8*NL0*1024);      // [16][296] bf16: k = 256 h | 32 x | 8 pad
    int* cL0 = cntp(ws, rb);
    int* cXa = cntp(ws, NRG + rb*2);
    int* cXb = cntp(ws, NRG + rb*2 + 1);
    const short* WH = (const short*)(ws + wsoff::WHH0);
    const short* WI = (const short*)(ws + wsoff::WIH0);
    for (int idx = tid; idx < 8*NL0*512; idx += 512){
      int slot = idx >> 9, le = idx & 511, ln = le >> 3, j = le & 7, lrr = ln & 15, qq = ln >> 4;
      int w2 = slot / NL0, i = slot % NL0;
      int kb = i % 9, t2 = i / 9, g = t2 % 3, cs = t2 / 3;
      int row = g*HE + w2*32 + cs*16 + lrr;
      wlds[idx] = (kb < 8) ? WH[(size_t)row*256 + kb*32 + qq*8 + j]
                           : WI[(size_t)row*32  + qq*8 + j];
    }
    for (int idx = tid; idx < RG*296; idx += 512) abuf[idx] = 0;
    v8s wreg[NR0];
    #pragma unroll
    for (int i = NL0; i < 54; ++i){
      int kb = i % 9, t2 = i / 9, g = t2 % 3, cs = t2 / 3;
      int row = g*HE + w*32 + cs*16 + lr;
      wreg[i-NL0] = (kb < 8) ? fragld(bfp(ws,wsoff::WHH0), (size_t)row*256 + kb*32 + q*8)
                             : fragld(bfp(ws,wsoff::WIH0), (size_t)row*32 + q*8);
    }
    const float* bih = f32p(ws,wsoff::BIH0);
    const float* bhh = f32p(ws,wsoff::BHH0);
    float birv[2], bizv[2], binv[2], bhnv[2];
    #pragma unroll
    for (int cs=0;cs<2;cs++){
      int d = w*32 + cs*16 + lr;
      birv[cs]=bih[d]+bhh[d]; bizv[cs]=bih[HE+d]+bhh[HE+d];
      binv[cs]=bih[2*HE+d];   bhnv[cs]=bhh[2*HE+d];
    }
    float h0a[2][4] = {};
    float* hTf = f32p(ws, wsoff::H0F0);
    bf16* ring0 = bfp(ws, wsoff::RING0) + (size_t)rb*4*RG*256;
    const bf16* Xs = bfp(ws,wsoff::XS);
    __syncthreads();
    for (int t = 0; t < 128; ++t){
      if (tid == 0 && t >= 4){          // ring0 depth 4 back-pressure
        pollge(cXa, t-3); pollge(cXb, t-3);
      }
      __syncthreads();                  // S1
      if (tid < 64){                    // stage x[t] into abuf k 256..287
        int row = tid >> 2, ck = tid & 3;
        v8s xv = fragld(Xs, ((size_t)t*NB + rowbase + row)*KX + ck*8);
        *(v8s*)(abuf + row*296 + 256 + ck*8) = xv;
      }
      __syncthreads();                  // S2
      v4f accr[2], accz[2], accxn[2], acchn[2];
      #pragma unroll
      for (int cs=0;cs<2;cs++){
        accr[cs]=(v4f){0,0,0,0}; accz[cs]=(v4f){0,0,0,0};
        accxn[cs]=(v4f){0,0,0,0}; acchn[cs]=(v4f){0,0,0,0};
      }
      #pragma unroll
      for (int kb=0;kb<9;kb++){
        v8s af = lds_frag8(abuf + lr*296 + kb*32 + q*8);
        #pragma unroll
        for (int cs=0;cs<2;cs++)
          #pragma unroll
          for (int g=0;g<3;g++){
            int i = (cs*3+g)*9 + kb;
            v8s b = (i < NL0) ? ldsfrag(wlds, w*NL0 + i, lane) : wreg[i-NL0];
            v4f* A = (g==0)?&accr[cs]:(g==1)?&accz[cs]:((kb<8)?&acchn[cs]:&accxn[cs]);
            *A = mfma16(af, b, *A);
          }
      }
      int mk[4];
      #pragma unroll
      for (int rr=0;rr<4;rr++) mk[rr] = maskT[(size_t)t*NB + rowbase + q*4 + rr];
      __syncthreads();                  // S3: all A reads done -> safe to overwrite h
      bf16* slot = ring0 + (size_t)(t&3)*RG*256;
      #pragma unroll
      for (int cs=0;cs<2;cs++){
        int d = w*32 + cs*16 + lr;
        #pragma unroll
        for (int rr=0;rr<4;rr++){
          int row = q*4 + rr;
          float rg = sigm(accr[cs][rr] + birv[cs]);
          float zg = sigm(accz[cs][rr] + bizv[cs]);
          float nn = tanh_f(accxn[cs][rr] + binv[cs] + rg*(acchn[cs][rr]+bhnv[cs]));
          float hv = (1.f-zg)*nn + zg*h0a[cs][rr];
          float h2 = mk[rr] ? hv : h0a[cs][rr];
          h0a[cs][rr] = h2;
          abuf[row*296 + d] = bf16bits(h2);
          stg_coh_pair(slot + ((size_t)row*256 + (d & ~1)), lr, h2);
          if (t == 127) hTf[(size_t)(rowbase+row)*HE + d] = h2;
        }
      }
      __syncthreads();                  // S4: ring stores drained (vmcnt0 per thread)
      if (tid == 0) cntset(cL0, t+1);
    }
  } else {
    // ---------------- LAYER 1 (+ fused MLP on col-half 0) ----------------
    constexpr int NL1 = 15;              // LDS weight tiles per wave (of 48)
    constexpr int NR1 = 48 - NL1;        // 33 register tiles (132 VGPR)
    // XCD-aware pairing: partner = id^8 (same bid%8 -> same XCD); logical (rb,ch) decoupled from bid.
    const int id = bid - NRG;
    const int grp = id >> 4, slot15 = id & 15;
    const int ch = slot15 >> 3, rb = grp*8 + (slot15 & 7);
    const int rowbase = rb*RG;
    short* wlds = (short*)smem;                                 // 8*15 KB
    short* abuf = (short*)(smem + 8*NL1*1024);                  // [16][520]: k = 256 h0 | 256 h1 | 8 pad
    short* w1s  = (short*)(smem + 8*NL1*1024 + RG*520*2);       // MLP W1 tiles, 16KB (ch0 only)
    int* cL0 = cntp(ws, rb);
    int* cXo = cntp(ws, NRG + rb*2 + ch);
    int* cXp = cntp(ws, NRG + rb*2 + (ch^1));
    const short* WX = (const short*)(ws + wsoff::WIH1);
    const short* WHs= (const short*)(ws + wsoff::WHH1);
    for (int idx = tid; idx < 8*NL1*512; idx += 512){
      int slot = idx >> 9, le = idx & 511, ln = le >> 3, j = le & 7, lrr = ln & 15, qq = ln >> 4;
      int w2 = slot / NL1, i = slot % NL1;
      int kb = i & 15, g = i >> 4;
      int row = g*HE + ch*128 + w2*16 + lrr;
      wlds[idx] = (kb < 8) ? WX [(size_t)row*256 + kb*32 + qq*8 + j]
                           : WHs[(size_t)row*256 + (kb-8)*32 + qq*8 + j];
    }
    if (ch == 0){
      const short* W1s = (const short*)(ws + wsoff::W1B);
      for (int idx = tid; idx < 16*512; idx += 512){
        int u = idx >> 9, le = idx & 511, ln = le >> 3, j = le & 7, lrr = ln & 15, qq = ln >> 4;
        int c = u >> 2, kb = u & 3;
        w1s[idx] = W1s[(size_t)(c*16 + lrr)*NH + kb*32 + qq*8 + j];
      }
    }
    for (int idx = tid; idx < RG*520; idx += 512) abuf[idx] = 0;
    v8s wreg[NR1];
    #pragma unroll
    for (int i = NL1; i < 48; ++i){
      int kb = i & 15, g = i >> 4;
      int row = g*HE + ch*128 + w*16 + lr;
      wreg[i-NL1] = (kb < 8) ? fragld(bfp(ws,wsoff::WIH1), (size_t)row*256 + kb*32 + q*8)
                             : fragld(bfp(ws,wsoff::WHH1), (size_t)row*256 + (kb-8)*32 + q*8);
    }
    const float* bih = f32p(ws,wsoff::BIH1);
    const float* bhh = f32p(ws,wsoff::BHH1);
    const int d = ch*128 + w*16 + lr;
    const float birv=bih[d]+bhh[d], bizv=bih[HE+d]+bhh[HE+d];
    const float binv=bih[2*HE+d],   bhnv=bhh[2*HE+d];
    float h1a[4] = {};
    float b1v[4], w20[4], w21[4];
    #pragma unroll
    for (int c=0;c<4;c++){
      int col=c*16+lr;
      b1v[c]=f32p(ws,wsoff::B1F)[col];
      w20[c]=f32p(ws,wsoff::W2F)[col]; w21[c]=f32p(ws,wsoff::W2F)[64+col];
    }
    const float b20 = f32p(ws,wsoff::B2F)[0], b21 = f32p(ws,wsoff::B2F)[1];
    float* hTf = f32p(ws, wsoff::H1F0);
    const bf16* ring0 = bfp(ws, wsoff::RING0) + (size_t)rb*4*RG*256;
    bf16* ring1o       = bfp(ws, wsoff::RING1) + (size_t)(rb*2+ch)*2*RG*128;
    const bf16* ring1p = bfp(ws, wsoff::RING1) + (size_t)(rb*2+(ch^1))*2*RG*128;
    float* encp = f32p(ws,wsoff::ENCP);
    __syncthreads();
    for (int s = 0; s < 128; ++s){
      if (tid == 0){
        pollge(cL0, s+1);                 // h0[s] published
        if (s >= 1) pollge(cXp, s);       // partner finished s-1 -> its h1 half published
      }
      __syncthreads();                    // S1
      {                                   // stage h0[s] (16x256) into abuf k 0..255
        const bf16* hs = ring0 + (size_t)(s&3)*RG*256;
        int row = tid >> 5, ck = tid & 31;
        v8s v = ldg_coh16(hs + (size_t)row*256 + ck*8);
        *(v8s*)(abuf + row*520 + ck*8) = v;
      }
      if (s >= 1 && tid < 256){           // stage partner h1 half (16x128)
        const bf16* hp = ring1p + (size_t)((s-1)&1)*RG*128;
        int row = tid >> 4, ck = tid & 15;
        v8s v = ldg_coh16(hp + (size_t)row*128 + ck*8);
        *(v8s*)(abuf + row*520 + 256 + (ch^1)*128 + ck*8) = v;
      }
      __syncthreads();                    // S2
      v4f accr=(v4f){0,0,0,0}, accz=(v4f){0,0,0,0};
      v4f accxn=(v4f){0,0,0,0}, acchn=(v4f){0,0,0,0};
      #pragma unroll
      for (int kb=0;kb<16;kb++){
        v8s af = lds_frag8(abuf + lr*520 + kb*32 + q*8);
        #pragma unroll
        for (int g=0;g<3;g++){
          int i = g*16 + kb;
          v8s b = (i < NL1) ? ldsfrag(wlds, w*NL1 + i, lane) : wreg[i-NL1];
          v4f* A = (g==0)?&accr:(g==1)?&accz:((kb<8)?&accxn:&acchn);
          *A = mfma16(af, b, *A);
        }
      }
      int mk[4];
      #pragma unroll
      for (int rr=0;rr<4;rr++) mk[rr] = maskT[(size_t)s*NB + rowbase + q*4 + rr];
      __syncthreads();                    // S3
      bf16* slot = ring1o + (size_t)(s&1)*RG*128;
      #pragma unroll
      for (int rr=0;rr<4;rr++){
        int row = q*4 + rr;
        float rg = sigm(accr[rr] + birv);
        float zg = sigm(accz[rr] + bizv);
        float nn = tanh_f(accxn[rr] + binv + rg*(acchn[rr]+bhnv));
        float hv = (1.f-zg)*nn + zg*h1a[rr];
        float h2 = mk[rr] ? hv : h1a[rr];
        h1a[rr] = h2;
        int ch_col = w*16 + lr;
        abuf[row*520 + 256 + ch*128 + ch_col] = bf16bits(h2);
        stg_coh_pair(slot + ((size_t)row*128 + (ch_col & ~1)), lr, h2);
        if (s == 127) hTf[(size_t)(rowbase+row)*HE + d] = h2;
      }
      __syncthreads();                    // S4: h1 stores drained
      if (tid == 0) cntset(cXo, s+1);
      // ---- fused MLP (needs h1[:, :128] = ch0's own half, already in abuf) ----
      if (ch == 0 && w == 0){
        int vl = maskT[(size_t)s*NB + rowbase + lr];
        v4f acc[4];
        #pragma unroll
        for (int c=0;c<4;c++) acc[c]=(v4f){0,0,0,0};
        #pragma unroll
        for (int kb=0;kb<4;kb++){
          v8s af = vl ? lds_frag8(abuf + lr*520 + 256 + kb*32 + q*8)
                      : (v8s){0,0,0,0,0,0,0,0};
          #pragma unroll
          for (int c=0;c<4;c++) acc[c] = mfma16(af, ldsfrag(w1s, c*4+kb, lane), acc[c]);
        }
        float* outp = encp + (size_t)s*NB*2;
        #pragma unroll
        for (int rr=0;rr<4;rr++){
          float p0=0.f, p1=0.f;
          #pragma unroll
          for (int c=0;c<4;c++){
            float hv = acc[c][rr] + b1v[c]; hv = hv>0.f ? hv : 0.f;
            p0 += hv*w20[c]; p1 += hv*w21[c];
          }
          #pragma unroll
          for (int m=1;m<16;m<<=1){ p0 += __shfl_xor(p0,m,64); p1 += __shfl_xor(p1,m,64); }
          if (lr == 0){
            int grow = rowbase + q*4 + rr;
            outp[(size_t)grow*2]   = softplusf(p0+b20);
            outp[(size_t)grow*2+1] = softplusf(p1+b21);
          }
        }
      }
    }
  }
}

// ================= decoder: round-1 structure, VALU tail with 4-chain ILP (r5 best: 1005 us) =================
__global__ __attribute__((amdgpu_flat_work_group_size(512,512), amdgpu_waves_per_eu(1)))
void k_decoder(char* ws, const void* eps, const void* feat, void* out){
  extern __shared__ __align__(16) char dsm[];
  short* s_h0b = (short*)dsm;                       // [32][HDS]      @0      10496
  short* s_h1b = s_h0b + 32*HDS;                    //                @10496  10496
  float* s_inp = (float*)(dsm + 20992);             // [64]           @20992  256
  float* s_red = (float*)(dsm + 21248);             // [128]          @21248  512
  short* s_wh  = (short*)(dsm + 21760);             // WH1 t0..7 frag @21760  122880
  short* s_cw0 = (short*)(dsm + 144640);            // [3][4][132]    @144640 3168
  short* s_cwx = (short*)(dsm + 147808);            //                        3168
  short* s_cwh = (short*)(dsm + 150976);            //                        3168
  float* s_tail= (float*)(dsm + 154144);            // [512]                  2048
  float* s_th  = (float*)(dsm + 156192);            // [2][32][4]             1024
  float* s_tt0 = (float*)(dsm + 157216);            // [4][10]                160
  float* s_tt1 = (float*)(dsm + 157376);            // [4][4]                 64

  const int isbf = *(const int*)(ws+wsoff::FLAG);
  const int tid = threadIdx.x;
  const int lane = tid & 63, w = tid >> 6, lr = lane & 15, q = lane >> 4;
  const int rowbase = blockIdx.x*32;
  constexpr size_t N0v = (size_t)NS*NB*127*2;

  const bf16* W0g  = bfp(ws,wsoff::WDHH0);
  const bf16* WX1g = bfp(ws,wsoff::WDIH1);

  // ---- phase A: zero + LDS staging ----
  for (int i = tid; i < 2*32*HDS; i += 512) s_h0b[i] = 0;
  {
    const short* src = (const short*)(ws + wsoff::WDHH1);
    for (int idx = tid; idx < 120*512; idx += 512){
      int u = idx >> 9, le = idx & 511, ln = le >> 3, e = le & 7, lrr = ln & 15, qq = ln >> 4;
      int kb = u % 5, t2 = u / 5, cc = t2 & 7, g = t2 >> 3;
      s_wh[idx] = src[(size_t)(g*GDP + cc*16 + lrr)*HDP + kb*32 + qq*8 + e];
    }
    const short* g0 = (const short*)(ws + wsoff::WDHH0);
    const short* gx = (const short*)(ws + wsoff::WDIH1);
    const short* gh = (const short*)(ws + wsoff::WDHH1);
    for (int i = tid; i < 3*4*132; i += 512){
      int k = i % 132, t2 = i / 132, c4 = t2 & 3, g = t2 >> 2;
      size_t so = (size_t)(g*GDP + 128 + c4)*HDP + k;
      s_cw0[i] = g0[so]; s_cwx[i] = gx[so]; s_cwh[i] = gh[so];
    }
  }
  if (tid < 4){
    const float* wih = f32p(ws,wsoff::WDIH0F);
    const float* bi0 = f32p(ws,wsoff::BDIH0); const float* bh0 = f32p(ws,wsoff::BDHH0);
    const float* bi1 = f32p(ws,wsoff::BDIH1); const float* bh1 = f32p(ws,wsoff::BDHH1);
    int dd = 128 + tid;
    float* T = s_tt0 + tid*10;
    T[0]=wih[(0*HD+dd)*2]; T[1]=wih[(0*HD+dd)*2+1];
    T[2]=wih[(1*HD+dd)*2]; T[3]=wih[(1*HD+dd)*2+1];
    T[4]=wih[(2*HD+dd)*2]; T[5]=wih[(2*HD+dd)*2+1];
    T[6]=bi0[dd]+bh0[dd]; T[7]=bi0[HD+dd]+bh0[HD+dd]; T[8]=bi0[2*HD+dd]; T[9]=bh0[2*HD+dd];
    float* T1 = s_tt1 + tid*4;
    T1[0]=bi1[dd]+bh1[dd]; T1[1]=bi1[HD+dd]+bh1[HD+dd]; T1[2]=bi1[2*HD+dd]; T1[3]=bh1[2*HD+dd];
  }
  if (tid < 64){
    int r0 = tid >> 1, c = tid & 1;
    int b = (rowbase + r0) & 1023;
    float v = f32p(ws,wsoff::ENCP)[((size_t)127*NB + b)*2 + c];
    s_inp[tid] = v;
    st_out(out, N0v + ((size_t)(rowbase+r0)*64)*2 + c, v, isbf);
  }
  __syncthreads();

  // ---- phase B: per-thread state init + RF weights ----
  const int d = w*16 + lr;   // always < 128
  float e0a[10], e1a[4];
  {
    const float* wih = f32p(ws,wsoff::WDIH0F);
    const float* bi0 = f32p(ws,wsoff::BDIH0); const float* bh0 = f32p(ws,wsoff::BDHH0);
    const float* bi1 = f32p(ws,wsoff::BDIH1); const float* bh1 = f32p(ws,wsoff::BDHH1);
    e0a[0]=wih[(0*HD+d)*2]; e0a[1]=wih[(0*HD+d)*2+1];
    e0a[2]=wih[(1*HD+d)*2]; e0a[3]=wih[(1*HD+d)*2+1];
    e0a[4]=wih[(2*HD+d)*2]; e0a[5]=wih[(2*HD+d)*2+1];
    e0a[6]=bi0[d]+bh0[d]; e0a[7]=bi0[HD+d]+bh0[HD+d]; e0a[8]=bi0[2*HD+d]; e0a[9]=bh0[2*HD+d];
    e1a[0]=bi1[d]+bh1[d]; e1a[1]=bi1[HD+d]+bh1[HD+d]; e1a[2]=bi1[2*HD+d]; e1a[3]=bh1[2*HD+d];
  }
  float h0a[2][4], h1a[2][4];
  {
    const float* h0T = f32p(ws,wsoff::H0F0);
    const float* h1T = f32p(ws,wsoff::H1F0);
    #pragma unroll
    for (int m=0;m<2;m++)
      #pragma unroll
      for (int r=0;r<4;r++){
        int row = m*16 + q*4 + r, grow = rowbase + row;
        int s = grow >> 10, b = grow & 1023;
        float e0 = ld_any(eps, ((size_t)(s*2+0)*NB + b)*NH + d, isbf);
        float e1 = ld_any(eps, ((size_t)(s*2+1)*NB + b)*NH + d, isbf);
        float v0 = e0*__expf(0.5f*h0T[(size_t)b*HE + NH + d]) + h0T[(size_t)b*HE + d];
        float v1 = e1*__expf(0.5f*h1T[(size_t)b*HE + NH + d]) + h1T[(size_t)b*HE + d];
        h0a[m][r] = v0; h1a[m][r] = v1;
        s_h0b[row*HDS + d] = bf16bits(v0);
        s_h1b[row*HDS + d] = bf16bits(v1);
      }
  }
  if (tid < 128){
    int c4 = tid >> 5, row = tid & 31;
    int b = (rowbase + row) & 1023;
    float fc = ld_any(feat, (size_t)b*3072 + 2048 + c4, isbf);
    s_th[row*4 + c4] = fc;
    s_th[128 + row*4 + c4] = fc;
    s_h0b[row*HDS + 128 + c4] = bf16bits(fc);
    s_h1b[row*HDS + 128 + c4] = bf16bits(fc);
  }
  v8s w0f[3][5], wxf[3][5];
  #pragma unroll
  for (int g=0;g<3;g++)
    #pragma unroll
    for (int kb=0;kb<5;kb++){
      size_t off = (size_t)(g*GDP + w*16 + lr)*HDP + kb*32 + q*8;
      w0f[g][kb] = fragld(W0g, off);
      wxf[g][kb] = fragld(WX1g, off);
    }
  v8s w1f[2][4]; float b1v[2], w20v[2], w21v[2];
  if (w == 5 || w == 6){
    const int tb = (w-5)*2;
    const bf16* W1g = bfp(ws,wsoff::W1B);
    #pragma unroll
    for (int ct=0;ct<2;ct++){
      #pragma unroll
      for (int kb=0;kb<4;kb++)
        w1f[ct][kb] = fragld(W1g, (size_t)((tb+ct)*16+lr)*NH + kb*32 + q*8);
      b1v[ct]  = f32p(ws,wsoff::B1F)[(tb+ct)*16+lr];
      w20v[ct] = f32p(ws,wsoff::W2F)[(tb+ct)*16+lr];
      w21v[ct] = f32p(ws,wsoff::W2F)[64+(tb+ct)*16+lr];
    }
  }
  const float b20 = f32p(ws,wsoff::B2F)[0], b21 = f32p(ws,wsoff::B2F)[1];
  __syncthreads();

  const int ttg = tid >> 7, ttc4 = (tid >> 5) & 3, ttrow = tid & 31;
  for (int k = 0; k < 63; ++k){
    // ---- P1: main MFMA + tail dots (read s_h0b old) ----
    v4f p1[3][2];
    #pragma unroll
    for (int g=0;g<3;g++){ p1[g][0]=(v4f){0,0,0,0}; p1[g][1]=(v4f){0,0,0,0}; }
    #pragma unroll
    for (int m=0;m<2;m++)
      #pragma unroll
      for (int kb=0;kb<5;kb++){
        v8s A = lds_frag8(s_h0b + (m*16+lr)*HDS + kb*32 + q*8);
        #pragma unroll
        for (int g=0;g<3;g++) p1[g][m] = mfma16(A, w0f[g][kb], p1[g][m]);
      }
    if (tid < 384){
      const unsigned* st = (const unsigned*)s_h0b + ttrow*(HDS/2);
      const unsigned* wp = (const unsigned*)s_cw0 + (ttg*4+ttc4)*66;
      float t0=0.f, t1=0.f, t2v=0.f, t3v=0.f;
      #pragma unroll 2
      for (int k2 = 0; k2 < 64; k2 += 4){
        unsigned sa=st[k2],   wa=wp[k2];
        unsigned sb=st[k2+1], wb=wp[k2+1];
        unsigned sc=st[k2+2], wc=wp[k2+2];
        unsigned sd=st[k2+3], wd=wp[k2+3];
        t0  += uasf(sa<<16)*uasf(wa<<16) + uasf(sa & 0xffff0000u)*uasf(wa & 0xffff0000u);
        t1  += uasf(sb<<16)*uasf(wb<<16) + uasf(sb & 0xffff0000u)*uasf(wb & 0xffff0000u);
        t2v += uasf(sc<<16)*uasf(wc<<16) + uasf(sc & 0xffff0000u)*uasf(wc & 0xffff0000u);
        t3v += uasf(sd<<16)*uasf(wd<<16) + uasf(sd & 0xffff0000u)*uasf(wd & 0xffff0000u);
      }
      { unsigned sa=st[64], wa=wp[64], sb=st[65], wb=wp[65];
        t0 += uasf(sa<<16)*uasf(wa<<16) + uasf(sa & 0xffff0000u)*uasf(wa & 0xffff0000u);
        t1 += uasf(sb<<16)*uasf(wb<<16) + uasf(sb & 0xffff0000u)*uasf(wb & 0xffff0000u); }
      s_tail[(ttg*4+ttc4)*32 + ttrow] = (t0+t1)+(t2v+t3v);
    }
    __syncthreads();
    // ---- P1 epilogue (write s_h0b new) ----
    #pragma unroll
    for (int m=0;m<2;m++)
      #pragma unroll
      for (int r=0;r<4;r++){
        int row = m*16 + q*4 + r;
        float i0 = s_inp[row*2], i1 = s_inp[row*2+1];
        float rr = sigm(i0*e0a[0]+i1*e0a[1] + p1[0][m][r] + e0a[6]);
        float zz = sigm(i0*e0a[2]+i1*e0a[3] + p1[1][m][r] + e0a[7]);
        float nn = tanh_f(i0*e0a[4]+i1*e0a[5] + e0a[8] + rr*(p1[2][m][r] + e0a[9]));
        float h = (1.f-zz)*nn + zz*h0a[m][r];
        h0a[m][r] = h;
        s_h0b[row*HDS + d] = bf16bits(h);
      }
    if (tid < 128){
      int c4 = tid >> 5, row = tid & 31;
      float ar = s_tail[(0*4+c4)*32+row], az = s_tail[(1*4+c4)*32+row], an = s_tail[(2*4+c4)*32+row];
      const float* T = s_tt0 + c4*10;
      float i0 = s_inp[row*2], i1 = s_inp[row*2+1];
      float rr = sigm(i0*T[0]+i1*T[1] + ar + T[6]);
      float zz = sigm(i0*T[2]+i1*T[3] + az + T[7]);
      float nn = tanh_f(i0*T[4]+i1*T[5] + T[8] + rr*(an + T[9]));
      float ho = s_th[row*4 + c4];
      float h = (1.f-zz)*nn + zz*ho;
      s_th[row*4 + c4] = h;
      s_h0b[row*HDS + 128 + c4] = bf16bits(h);
    }
    __syncthreads();
    // ---- P2: main MFMA + tail dots (read s_h0b new, s_h1b old) ----
    v4f p2[4][2];
    #pragma unroll
    for (int g=0;g<4;g++){ p2[g][0]=(v4f){0,0,0,0}; p2[g][1]=(v4f){0,0,0,0}; }
    #pragma unroll
    for (int m=0;m<2;m++)
      #pragma unroll
      for (int kb=0;kb<5;kb++){
        v8s ax = lds_frag8(s_h0b + (m*16+lr)*HDS + kb*32 + q*8);
        v8s ah = lds_frag8(s_h1b + (m*16+lr)*HDS + kb*32 + q*8);
        #pragma unroll
        for (int g=0;g<3;g++){
          int aix = (g==2) ? 2 : g, aih = (g==2) ? 3 : g;
          p2[aix][m] = mfma16(ax, wxf[g][kb], p2[aix][m]);
          p2[aih][m] = mfma16(ah, ldsfrag(s_wh, (g*8+w)*5 + kb, lane), p2[aih][m]);
        }
      }
    {
      const unsigned* h0p = (const unsigned*)s_h0b + ttrow*(HDS/2);
      const unsigned* h1p = (const unsigned*)s_h1b + ttrow*(HDS/2);
      float td = 0.f;
      if (ttg <= 1){
        const unsigned* wx = (const unsigned*)s_cwx + (ttg*4+ttc4)*66;
        const unsigned* wh = (const unsigned*)s_cwh + (ttg*4+ttc4)*66;
        float x0=0.f, x1=0.f, y0=0.f, y1=0.f;
        #pragma unroll 2
        for (int k2 = 0; k2 < 66; k2 += 2){
          unsigned sa=h0p[k2],   wa=wx[k2];
          unsigned sb=h0p[k2+1], wb=wx[k2+1];
          unsigned ha=h1p[k2],   va=wh[k2];
          unsigned hb=h1p[k2+1], vb=wh[k2+1];
          x0 += uasf(sa<<16)*uasf(wa<<16) + uasf(sa & 0xffff0000u)*uasf(wa & 0xffff0000u);
          x1 += uasf(sb<<16)*uasf(wb<<16) + uasf(sb & 0xffff0000u)*uasf(wb & 0xffff0000u);
          y0 += uasf(ha<<16)*uasf(va<<16) + uasf(ha & 0xffff0000u)*uasf(va & 0xffff0000u);
          y1 += uasf(hb<<16)*uasf(vb<<16) + uasf(hb & 0xffff0000u)*uasf(vb & 0xffff0000u);
        }
        td = (x0+x1)+(y0+y1);
      } else if (ttg == 2){
        const unsigned* wx = (const unsigned*)s_cwx + (2*4+ttc4)*66;
        float x0=0.f, x1=0.f;
        #pragma unroll 2
        for (int k2 = 0; k2 < 66; k2 += 2){
          unsigned sa=h0p[k2], wa=wx[k2], sb=h0p[k2+1], wb=wx[k2+1];
          x0 += uasf(sa<<16)*uasf(wa<<16) + uasf(sa & 0xffff0000u)*uasf(wa & 0xffff0000u);
          x1 += uasf(sb<<16)*uasf(wb<<16) + uasf(sb & 0xffff0000u)*uasf(wb & 0xffff0000u);
        }
        td = x0+x1;
      } else {
        const unsigned* wh = (const unsigned*)s_cwh + (2*4+ttc4)*66;
        float y0=0.f, y1=0.f;
        #pragma unroll 2
        for (int k2 = 0; k2 < 66; k2 += 2){
          unsigned sa=h1p[k2], wa=wh[k2], sb=h1p[k2+1], wb=wh[k2+1];
          y0 += uasf(sa<<16)*uasf(wa<<16) + uasf(sa & 0xffff0000u)*uasf(wa & 0xffff0000u);
          y1 += uasf(sb<<16)*uasf(wb<<16) + uasf(sb & 0xffff0000u)*uasf(wb & 0xffff0000u);
        }
        td = y0+y1;
      }
      s_tail[(ttg*4+ttc4)*32 + ttrow] = td;
    }
    __syncthreads();
    // ---- P2 epilogue (write s_h1b new) ----
    #pragma unroll
    for (int m=0;m<2;m++)
      #pragma unroll
      for (int r=0;r<4;r++){
        int row = m*16 + q*4 + r;
        float rr = sigm(p2[0][m][r] + e1a[0]);
        float zz = sigm(p2[1][m][r] + e1a[1]);
        float nn = tanh_f(p2[2][m][r] + e1a[2] + rr*(p2[3][m][r] + e1a[3]));
        float h = (1.f-zz)*nn + zz*h1a[m][r];
        h1a[m][r] = h;
        s_h1b[row*HDS + d] = bf16bits(h);
      }
    if (tid < 128){
      int c4 = tid >> 5, row = tid & 31;
      float tr = s_tail[(0*4+c4)*32+row], tz = s_tail[(1*4+c4)*32+row];
      float txn = s_tail[(2*4+c4)*32+row], thn = s_tail[(3*4+c4)*32+row];
      const float* T1 = s_tt1 + c4*4;
      float rr = sigm(tr + T1[0]);
      float zz = sigm(tz + T1[1]);
      float nn = tanh_f(txn + T1[2] + rr*(thn + T1[3]));
      float ho = s_th[128 + row*4 + c4];
      float h = (1.f-zz)*nn + zz*ho;
      s_th[128 + row*4 + c4] = h;
      s_h1b[row*HDS + 128 + c4] = bf16bits(h);
    }
    __syncthreads();
    // ---- P3: MLP halves on waves 5,6 ----
    if (w == 5 || w == 6){
      v4f a3[2][2];
      #pragma unroll
      for (int ct=0;ct<2;ct++){ a3[ct][0]=(v4f){0,0,0,0}; a3[ct][1]=(v4f){0,0,0,0}; }
      #pragma unroll
      for (int m=0;m<2;m++)
        #pragma unroll
        for (int kb=0;kb<4;kb++){
          v8s A = lds_frag8(s_h1b + (m*16+lr)*HDS + kb*32 + q*8);
          #pragma unroll
          for (int ct=0;ct<2;ct++) a3[ct][m] = mfma16(A, w1f[ct][kb], a3[ct][m]);
        }
      #pragma unroll
      for (int m=0;m<2;m++)
        #pragma unroll
        for (int r=0;r<4;r++){
          float p0 = 0.f, p1v = 0.f;
          #pragma unroll
          for (int ct=0;ct<2;ct++){
            float hv = a3[ct][m][r] + b1v[ct]; hv = hv > 0.f ? hv : 0.f;
            p0 += hv*w20v[ct]; p1v += hv*w21v[ct];
          }
          #pragma unroll
          for (int mm=1;mm<16;mm<<=1){ p0 += __shfl_xor(p0,mm,64); p1v += __shfl_xor(p1v,mm,64); }
          if (lr == 0){
            int row = m*16 + q*4 + r;
            s_red[(w-5)*64 + row*2]   = p0;
            s_red[(w-5)*64 + row*2+1] = p1v;
          }
        }
    }
    __syncthreads();
    // ---- P4: combine + feedback + out ----
    if (tid < 64){
      int row = tid >> 1, c = tid & 1;
      float p = s_red[row*2 + c] + s_red[64 + row*2 + c];
      float v = softplusf(p + (c ? b21 : b20));
      s_inp[tid] = v;
      st_out(out, N0v + ((size_t)(rowbase+row)*64 + (k+1))*2 + c, v, isbf);
    }
    __syncthreads();
  }
}

// ---------- encoder-part output assembly ----------
__global__ void k_assemble_enc(char* ws, void* out){
  int isbf = *(const int*)(ws+wsoff::FLAG);
  const float* encp = f32p(ws,wsoff::ENCP);
  constexpr size_t N0v = (size_t)NS*NB*127*2;
  for (size_t i = (size_t)blockIdx.x*blockDim.x + threadIdx.x; i < N0v;
       i += (size_t)gridDim.x*blockDim.x){
    int c = (int)(i & 1); size_t qq = i >> 1;
    int tt = (int)(qq % 127); size_t q2 = qq / 127; int b = (int)(q2 & 1023);
    st_out(out, i, encp[((size_t)tt*NB + b)*2 + c], isbf);
  }
}

extern "C" void kernel_launch(void* const* d_in, const int* in_sizes, int n_in,
                              void* d_out, int out_size, void* d_ws, size_t ws_size,
                              hipStream_t stream) {
  char* ws = (char*)d_ws;
  const int* mask = (const int*)d_in[2];
  auto gb = [](size_t n){ return dim3((unsigned)((n + 255)/256)); };

  hipMemsetAsync(ws+wsoff::CNT, 0, 192*64, stream);

  k_detect<<<1,64,0,stream>>>(ws, d_in[3]);

  k_stage_xs   <<<gb((size_t)NT*NB*KX),256,0,stream>>>(ws, d_in[0], d_in[1]);
  k_stage_maskT<<<gb((size_t)NT*NB),256,0,stream>>>(ws, mask);
  k_stage_pad<<<gb(768*32) ,256,0,stream>>>(ws, d_in[7],  wsoff::WIH0, 768, 18, 32);
  k_stage_pad<<<gb(768*256),256,0,stream>>>(ws, d_in[8],  wsoff::WHH0, 768, 256, 256);
  k_stage_pad<<<gb(768*256),256,0,stream>>>(ws, d_in[11], wsoff::WIH1, 768, 256, 256);
  k_stage_pad<<<gb(768*256),256,0,stream>>>(ws, d_in[12], wsoff::WHH1, 768, 256, 256);
  k_stage_pad<<<gb(64*128) ,256,0,stream>>>(ws, d_in[23], wsoff::W1B,  64, 128, 128);
  k_stage_dec<<<gb(432*HDP),256,0,stream>>>(ws, d_in[16], wsoff::WDHH0);
  k_stage_dec<<<gb(432*HDP),256,0,stream>>>(ws, d_in[19], wsoff::WDIH1);
  k_stage_dec<<<gb(432*HDP),256,0,stream>>>(ws, d_in[20], wsoff::WDHH1);

  SmallSegs ss;
  const void* srcs[12] = {d_in[9],d_in[10],d_in[13],d_in[14],d_in[15],
                          d_in[17],d_in[18],d_in[21],d_in[22],
                          d_in[24],d_in[25],d_in[26]};
  const size_t offs[12] = {wsoff::BIH0,wsoff::BHH0,wsoff::BIH1,wsoff::BHH1,wsoff::WDIH0F,
                           wsoff::BDIH0,wsoff::BDHH0,wsoff::BDIH1,wsoff::BDHH1,
                           wsoff::B1F,wsoff::W2F,wsoff::B2F};
  const int ns[12] = {768,768,768,768,792,396,396,396,396,64,128,2};
  for (int i=0;i<12;i++){ ss.src[i]=srcs[i]; ss.dstoff[i]=(int)offs[i]; ss.n[i]=ns[i]; }
  k_stage_small<<<12,256,0,stream>>>(ws, ss);

  hipFuncSetAttribute(reinterpret_cast<const void*>(k_encoder),
                      hipFuncAttributeMaxDynamicSharedMemorySize, ENC_LDS);
  hipFuncSetAttribute(reinterpret_cast<const void*>(k_decoder),
                      hipFuncAttributeMaxDynamicSharedMemorySize, 157440);

  k_encoder<<<192,512,ENC_LDS,stream>>>(ws);
  k_decoder<<<256,512,157440,stream>>>(ws, d_in[3], d_in[1], d_out);
  k_assemble_enc<<<2048,256,0,stream>>>(ws, d_out);
}

// Round 10
// 1818.819 us; speedup vs baseline: 1.2562x; 1.0264x over previous
//
#include <hip/hip_runtime.h>
#include <hip/hip_bf16.h>
#include <math.h>

typedef __hip_bfloat16 bf16;
typedef short v8s __attribute__((ext_vector_type(8)));
typedef float v4f __attribute__((ext_vector_type(4)));

#define NB   1024
#define NT   128
#define NH   128
#define HE   256
#define HD   132
#define HDP  160
#define HDS  164
#define GDP  144
#define NS   8
#define KX   32
#define RG   16          // batch rows per encoder row-group
#define NRG  64          // row groups (64*16 = 1024)

namespace wsoff {
constexpr size_t al(size_t x){ return (x + 255) & ~size_t(255); }
constexpr size_t FLAG  = 0;
constexpr size_t CNT   = 256;                  // 192 counters x 64B
constexpr size_t XS    = al(CNT + 192*64);
constexpr size_t MASKT = al(XS    + (size_t)NT*NB*KX*2);   // int32 [NT][NB]
constexpr size_t WIH0  = al(MASKT + (size_t)NT*NB*4);
constexpr size_t WHH0  = al(WIH0  + 768*32*2);
constexpr size_t WIH1  = al(WHH0  + 768*256*2);
constexpr size_t WHH1  = al(WIH1  + 768*256*2);
constexpr size_t BIH0  = al(WHH1  + 768*256*2);
constexpr size_t BHH0  = al(BIH0  + 768*4);
constexpr size_t BIH1  = al(BHH0  + 768*4);
constexpr size_t BHH1  = al(BIH1  + 768*4);
constexpr size_t WDHH0 = al(BHH1  + 768*4);
constexpr size_t WDIH1 = al(WDHH0 + 432*HDP*2);
constexpr size_t WDHH1 = al(WDIH1 + 432*HDP*2);
constexpr size_t WDIH0F= al(WDHH1 + 432*HDP*2);
constexpr size_t BDIH0 = al(WDIH0F+ 792*4);
constexpr size_t BDHH0 = al(BDIH0 + 396*4);
constexpr size_t BDIH1 = al(BDHH0 + 396*4);
constexpr size_t BDHH1 = al(BDIH1 + 396*4);
constexpr size_t W1B   = al(BDHH1 + 396*4);
constexpr size_t B1F   = al(W1B   + 64*128*2);
constexpr size_t W2F   = al(B1F   + 64*4);
constexpr size_t B2F   = al(W2F   + 128*4);
constexpr size_t H0F0  = al(B2F   + 2*4);
constexpr size_t H1F0  = al(H0F0  + (size_t)NB*HE*4);
constexpr size_t RING0 = al(H1F0  + (size_t)NB*HE*4);          // 64 grp x 4 slot x 16x256 bf16
constexpr size_t RING1 = al(RING0 + (size_t)NRG*4*RG*256*2);   // 128 slots (rb*2+ch) x 2 x 16x128 bf16
constexpr size_t ENCP  = al(RING1 + (size_t)128*2*RG*128*2);
}

// ---------- helpers ----------
__device__ __forceinline__ float ld_any(const void* p, size_t i, int isbf){
  return isbf ? __bfloat162float(((const bf16*)p)[i]) : ((const float*)p)[i];
}
__device__ __forceinline__ void st_out(void* out, size_t i, float v, int isbf){
  if (isbf) ((bf16*)out)[i] = __float2bfloat16(v); else ((float*)out)[i] = v;
}
__device__ __forceinline__ float sigm(float x){ return 1.0f/(1.0f + __expf(-x)); }
__device__ __forceinline__ float tanh_f(float x){
  float t = __expf(2.0f*x); return 1.0f - 2.0f/(t+1.0f);
}
__device__ __forceinline__ float softplusf(float x){ return x>20.f ? x : log1pf(__expf(x)); }
__device__ __forceinline__ v4f mfma16(v8s a, v8s b, v4f c){
  return __builtin_amdgcn_mfma_f32_16x16x32_bf16(a,b,c,0,0,0);
}
__device__ __forceinline__ v8s fragld(const bf16* base, size_t elem_off){
  return *reinterpret_cast<const v8s*>(base + elem_off);
}
__device__ __forceinline__ v8s ldsfrag(const short* sm, int unit, int lane){
  return *reinterpret_cast<const v8s*>(sm + (unit<<9) + (lane<<3));
}
__device__ __forceinline__ v8s lds_frag8(const short* p){
  union { long long l[2]; v8s s; } r;
  r.l[0] = *(const long long*)(p);
  r.l[1] = *(const long long*)(p + 4);
  return r.s;
}
__device__ __forceinline__ short bf16bits(float v){
  bf16 h = __float2bfloat16(v); short s; __builtin_memcpy(&s,&h,2); return s;
}
__device__ __forceinline__ float uasf(unsigned u){ float f; __builtin_memcpy(&f,&u,4); return f; }
__device__ __forceinline__ v8s ldg_coh16(const bf16* p){
  union { unsigned long long u[2]; v8s s; } r;
  const unsigned long long* q = (const unsigned long long*)p;
  r.u[0] = __hip_atomic_load(q+0, __ATOMIC_RELAXED, __HIP_MEMORY_SCOPE_AGENT);
  r.u[1] = __hip_atomic_load(q+1, __ATOMIC_RELAXED, __HIP_MEMORY_SCOPE_AGENT);
  return r.s;
}
__device__ __forceinline__ void stg_coh_pair(bf16* base_even, int lr, float v){
  bf16 h = __float2bfloat16(v);
  unsigned vv; { unsigned short b; __builtin_memcpy(&b, &h, 2); vv = b; }
  unsigned ov = (unsigned)__shfl_xor((int)vv, 1, 64);
  if (!(lr & 1))
    __hip_atomic_store((unsigned*)base_even, vv | (ov<<16), __ATOMIC_RELAXED, __HIP_MEMORY_SCOPE_AGENT);
}
__device__ __forceinline__ float*  f32p(char* ws, size_t off){ return (float*)(ws+off); }
__device__ __forceinline__ bf16*   bfp (char* ws, size_t off){ return (bf16*)(ws+off); }

// ---------- counters ----------
__device__ __forceinline__ int* cntp(char* ws, int idx){
  return (int*)(ws + wsoff::CNT + (size_t)idx*64);
}
__device__ __forceinline__ void pollge(int* f, int v){
  while (__hip_atomic_load(f, __ATOMIC_RELAXED, __HIP_MEMORY_SCOPE_AGENT) < v)
    __builtin_amdgcn_s_sleep(1);
}
__device__ __forceinline__ void cntset(int* f, int v){
  __hip_atomic_store(f, v, __ATOMIC_RELAXED, __HIP_MEMORY_SCOPE_AGENT);
}

// ---------- dtype detection ----------
__global__ void k_detect(char* ws, const void* eps){
  const unsigned short* p = (const unsigned short*)eps;
  int lane = threadIdx.x;
  unsigned short u = p[2*lane];
  int e = (u>>7)&0xFF;
  bool pl = (e>=118 && e<=130);
  unsigned long long m = __ballot(pl);
  if (lane==0) *(int*)(ws+wsoff::FLAG) = (__popcll(m) >= 32) ? 1 : 0;
}

// ---------- staging ----------
__global__ void k_stage_xs(char* ws, const void* x, const void* feat){
  int isbf = *(const int*)(ws+wsoff::FLAG);
  size_t i = (size_t)blockIdx.x*blockDim.x + threadIdx.x;
  if (i >= (size_t)NT*NB*KX) return;
  int c = i % KX; size_t q = i / KX; int b = q % NB; int t = q / NB;
  float v = 0.f;
  if (c < 2)        v = ld_any(x,    ((size_t)b*NT + t)*2 + c, isbf);
  else if (c < 18)  v = ld_any(feat, ((size_t)b*192 + t)*16 + (c-2), isbf);
  ((bf16*)(ws+wsoff::XS))[i] = __float2bfloat16(v);
}
__global__ void k_stage_maskT(char* ws, const int* mask){
  size_t i = (size_t)blockIdx.x*blockDim.x + threadIdx.x;
  if (i >= (size_t)NT*NB) return;
  int b = i % NB, t = i / NB;
  ((int*)(ws+wsoff::MASKT))[i] = mask[(size_t)b*NT + t];
}
__global__ void k_stage_pad(char* ws, const void* src, size_t dstoff, int R, int SC, int DC){
  int isbf = *(const int*)(ws+wsoff::FLAG);
  size_t i = (size_t)blockIdx.x*blockDim.x + threadIdx.x;
  if (i >= (size_t)R*DC) return;
  int r = i / DC, c = i % DC;
  float v = (c < SC) ? ld_any(src, (size_t)r*SC + c, isbf) : 0.f;
  ((bf16*)(ws+dstoff))[i] = __float2bfloat16(v);
}
__global__ void k_stage_dec(char* ws, const void* src, size_t dstoff){
  int isbf = *(const int*)(ws+wsoff::FLAG);
  size_t i = (size_t)blockIdx.x*blockDim.x + threadIdx.x;
  if (i >= (size_t)432*HDP) return;
  int R = i / HDP, c = i % HDP;
  int g = R / GDP, ii = R % GDP;
  float v = (ii < HD && c < HD) ? ld_any(src, ((size_t)(g*HD+ii))*HD + c, isbf) : 0.f;
  ((bf16*)(ws+dstoff))[i] = __float2bfloat16(v);
}
struct SmallSegs { const void* src[12]; int dstoff[12]; int n[12]; };
__global__ void k_stage_small(char* ws, SmallSegs segs){
  int isbf = *(const int*)(ws+wsoff::FLAG);
  int s = blockIdx.x;
  float* dst = (float*)(ws + (size_t)segs.dstoff[s]);
  for (int i = threadIdx.x; i < segs.n[s]; i += blockDim.x)
    dst[i] = ld_any(segs.src[s], i, isbf);
}

// ================= persistent encoder: row-ownership, weights resident per CU =================
// XCD-aware pairing (r9). This round: S1 barrier removed in both layers; polls are per-thread
// at point of use (dependencies on abuf regions already covered by S3/S4 barriers).
#define ENC_LDS 156928
__global__ __attribute__((amdgpu_flat_work_group_size(512,512), amdgpu_waves_per_eu(1)))
void k_encoder(char* ws){
  extern __shared__ __align__(16) char smem[];
  const int bid = blockIdx.x, tid = threadIdx.x;
  const int lane = tid & 63, w = tid >> 6, lr = lane & 15, q = lane >> 4;
  const int* maskT = (const int*)(ws + wsoff::MASKT);

  if (bid < NRG){
    // ---------------- LAYER 0 ----------------
    constexpr int NL0 = 18;              // LDS weight tiles per wave (of 54)
    constexpr int NR0 = 54 - NL0;        // 36 register tiles (144 VGPR)
    const int rb = bid, rowbase = rb*RG;
    short* wlds = (short*)smem;                     // 8*18 KB
    short* abuf = (short*)(smem + 8*NL0*1024);      // [16][296] bf16: k = 256 h | 32 x | 8 pad
    int* cL0 = cntp(ws, rb);
    int* cXa = cntp(ws, NRG + rb*2);
    int* cXb = cntp(ws, NRG + rb*2 + 1);
    const short* WH = (const short*)(ws + wsoff::WHH0);
    const short* WI = (const short*)(ws + wsoff::WIH0);
    for (int idx = tid; idx < 8*NL0*512; idx += 512){
      int slot = idx >> 9, le = idx & 511, ln = le >> 3, j = le & 7, lrr = ln & 15, qq = ln >> 4;
      int w2 = slot / NL0, i = slot % NL0;
      int kb = i % 9, t2 = i / 9, g = t2 % 3, cs = t2 / 3;
      int row = g*HE + w2*32 + cs*16 + lrr;
      wlds[idx] = (kb < 8) ? WH[(size_t)row*256 + kb*32 + qq*8 + j]
                           : WI[(size_t)row*32  + qq*8 + j];
    }
    for (int idx = tid; idx < RG*296; idx += 512) abuf[idx] = 0;
    v8s wreg[NR0];
    #pragma unroll
    for (int i = NL0; i < 54; ++i){
      int kb = i % 9, t2 = i / 9, g = t2 % 3, cs = t2 / 3;
      int row = g*HE + w*32 + cs*16 + lr;
      wreg[i-NL0] = (kb < 8) ? fragld(bfp(ws,wsoff::WHH0), (size_t)row*256 + kb*32 + q*8)
                             : fragld(bfp(ws,wsoff::WIH0), (size_t)row*32 + q*8);
    }
    const float* bih = f32p(ws,wsoff::BIH0);
    const float* bhh = f32p(ws,wsoff::BHH0);
    float birv[2], bizv[2], binv[2], bhnv[2];
    #pragma unroll
    for (int cs=0;cs<2;cs++){
      int d = w*32 + cs*16 + lr;
      birv[cs]=bih[d]+bhh[d]; bizv[cs]=bih[HE+d]+bhh[HE+d];
      binv[cs]=bih[2*HE+d];   bhnv[cs]=bhh[2*HE+d];
    }
    float h0a[2][4] = {};
    float* hTf = f32p(ws, wsoff::H0F0);
    bf16* ring0 = bfp(ws, wsoff::RING0) + (size_t)rb*4*RG*256;
    const bf16* Xs = bfp(ws,wsoff::XS);
    __syncthreads();
    for (int t = 0; t < 128; ++t){
      // (S1 barrier removed: x region's prior readers passed S3/S4 of step t-1)
      if (tid < 64){                    // stage x[t] into abuf k 256..287
        int row = tid >> 2, ck = tid & 3;
        v8s xv = fragld(Xs, ((size_t)t*NB + rowbase + row)*KX + ck*8);
        *(v8s*)(abuf + row*296 + 256 + ck*8) = xv;
      }
      __syncthreads();                  // S2
      v4f accr[2], accz[2], accxn[2], acchn[2];
      #pragma unroll
      for (int cs=0;cs<2;cs++){
        accr[cs]=(v4f){0,0,0,0}; accz[cs]=(v4f){0,0,0,0};
        accxn[cs]=(v4f){0,0,0,0}; acchn[cs]=(v4f){0,0,0,0};
      }
      #pragma unroll
      for (int kb=0;kb<9;kb++){
        v8s af = lds_frag8(abuf + lr*296 + kb*32 + q*8);
        #pragma unroll
        for (int cs=0;cs<2;cs++)
          #pragma unroll
          for (int g=0;g<3;g++){
            int i = (cs*3+g)*9 + kb;
            v8s b = (i < NL0) ? ldsfrag(wlds, w*NL0 + i, lane) : wreg[i-NL0];
            v4f* A = (g==0)?&accr[cs]:(g==1)?&accz[cs]:((kb<8)?&acchn[cs]:&accxn[cs]);
            *A = mfma16(af, b, *A);
          }
      }
      int mk[4];
      #pragma unroll
      for (int rr=0;rr<4;rr++) mk[rr] = maskT[(size_t)t*NB + rowbase + q*4 + rr];
      __syncthreads();                  // S3: all A reads done -> safe to overwrite h
      if (t >= 4){                      // ring0 depth-4 back-pressure, per-thread
        pollge(cXa, t-3); pollge(cXb, t-3);
      }
      bf16* slot = ring0 + (size_t)(t&3)*RG*256;
      #pragma unroll
      for (int cs=0;cs<2;cs++){
        int d = w*32 + cs*16 + lr;
        #pragma unroll
        for (int rr=0;rr<4;rr++){
          int row = q*4 + rr;
          float rg = sigm(accr[cs][rr] + birv[cs]);
          float zg = sigm(accz[cs][rr] + bizv[cs]);
          float nn = tanh_f(accxn[cs][rr] + binv[cs] + rg*(acchn[cs][rr]+bhnv[cs]));
          float hv = (1.f-zg)*nn + zg*h0a[cs][rr];
          float h2 = mk[rr] ? hv : h0a[cs][rr];
          h0a[cs][rr] = h2;
          abuf[row*296 + d] = bf16bits(h2);
          stg_coh_pair(slot + ((size_t)row*256 + (d & ~1)), lr, h2);
          if (t == 127) hTf[(size_t)(rowbase+row)*HE + d] = h2;
        }
      }
      __syncthreads();                  // S4: ring stores drained (vmcnt0 per thread)
      if (tid == 0) cntset(cL0, t+1);
    }
  } else {
    // ---------------- LAYER 1 (+ fused MLP on col-half 0) ----------------
    constexpr int NL1 = 15;              // LDS weight tiles per wave (of 48)
    constexpr int NR1 = 48 - NL1;        // 33 register tiles (132 VGPR)
    // XCD-aware pairing: partner = id^8 (same bid%8 -> same XCD); logical (rb,ch) decoupled from bid.
    const int id = bid - NRG;
    const int grp = id >> 4, slot15 = id & 15;
    const int ch = slot15 >> 3, rb = grp*8 + (slot15 & 7);
    const int rowbase = rb*RG;
    short* wlds = (short*)smem;                                 // 8*15 KB
    short* abuf = (short*)(smem + 8*NL1*1024);                  // [16][520]: k = 256 h0 | 256 h1 | 8 pad
    short* w1s  = (short*)(smem + 8*NL1*1024 + RG*520*2);       // MLP W1 tiles, 16KB (ch0 only)
    int* cL0 = cntp(ws, rb);
    int* cXo = cntp(ws, NRG + rb*2 + ch);
    int* cXp = cntp(ws, NRG + rb*2 + (ch^1));
    const short* WX = (const short*)(ws + wsoff::WIH1);
    const short* WHs= (const short*)(ws + wsoff::WHH1);
    for (int idx = tid; idx < 8*NL1*512; idx += 512){
      int slot = idx >> 9, le = idx & 511, ln = le >> 3, j = le & 7, lrr = ln & 15, qq = ln >> 4;
      int w2 = slot / NL1, i = slot % NL1;
      int kb = i & 15, g = i >> 4;
      int row = g*HE + ch*128 + w2*16 + lrr;
      wlds[idx] = (kb < 8) ? WX [(size_t)row*256 + kb*32 + qq*8 + j]
                           : WHs[(size_t)row*256 + (kb-8)*32 + qq*8 + j];
    }
    if (ch == 0){
      const short* W1s = (const short*)(ws + wsoff::W1B);
      for (int idx = tid; idx < 16*512; idx += 512){
        int u = idx >> 9, le = idx & 511, ln = le >> 3, j = le & 7, lrr = ln & 15, qq = ln >> 4;
        int c = u >> 2, kb = u & 3;
        w1s[idx] = W1s[(size_t)(c*16 + lrr)*NH + kb*32 + qq*8 + j];
      }
    }
    for (int idx = tid; idx < RG*520; idx += 512) abuf[idx] = 0;
    v8s wreg[NR1];
    #pragma unroll
    for (int i = NL1; i < 48; ++i){
      int kb = i & 15, g = i >> 4;
      int row = g*HE + ch*128 + w*16 + lr;
      wreg[i-NL1] = (kb < 8) ? fragld(bfp(ws,wsoff::WIH1), (size_t)row*256 + kb*32 + q*8)
                             : fragld(bfp(ws,wsoff::WHH1), (size_t)row*256 + (kb-8)*32 + q*8);
    }
    const float* bih = f32p(ws,wsoff::BIH1);
    const float* bhh = f32p(ws,wsoff::BHH1);
    const int d = ch*128 + w*16 + lr;
    const float birv=bih[d]+bhh[d], bizv=bih[HE+d]+bhh[HE+d];
    const float binv=bih[2*HE+d],   bhnv=bhh[2*HE+d];
    float h1a[4] = {};
    float b1v[4], w20[4], w21[4];
    #pragma unroll
    for (int c=0;c<4;c++){
      int col=c*16+lr;
      b1v[c]=f32p(ws,wsoff::B1F)[col];
      w20[c]=f32p(ws,wsoff::W2F)[col]; w21[c]=f32p(ws,wsoff::W2F)[64+col];
    }
    const float b20 = f32p(ws,wsoff::B2F)[0], b21 = f32p(ws,wsoff::B2F)[1];
    float* hTf = f32p(ws, wsoff::H1F0);
    const bf16* ring0 = bfp(ws, wsoff::RING0) + (size_t)rb*4*RG*256;
    bf16* ring1o       = bfp(ws, wsoff::RING1) + (size_t)(rb*2+ch)*2*RG*128;
    const bf16* ring1p = bfp(ws, wsoff::RING1) + (size_t)(rb*2+(ch^1))*2*RG*128;
    float* encp = f32p(ws,wsoff::ENCP);
    __syncthreads();
    for (int s = 0; s < 128; ++s){
      // (S1 barrier removed: each staging thread polls at point of use)
      {                                   // stage h0[s] (16x256) into abuf k 0..255
        pollge(cL0, s+1);                 // h0[s] published (per-thread)
        const bf16* hs = ring0 + (size_t)(s&3)*RG*256;
        int row = tid >> 5, ck = tid & 31;
        v8s v = ldg_coh16(hs + (size_t)row*256 + ck*8);
        *(v8s*)(abuf + row*520 + ck*8) = v;
      }
      if (s >= 1 && tid < 256){           // stage partner h1 half (16x128)
        pollge(cXp, s);                   // partner finished s-1 (per-thread)
        const bf16* hp = ring1p + (size_t)((s-1)&1)*RG*128;
        int row = tid >> 4, ck = tid & 15;
        v8s v = ldg_coh16(hp + (size_t)row*128 + ck*8);
        *(v8s*)(abuf + row*520 + 256 + (ch^1)*128 + ck*8) = v;
      }
      __syncthreads();                    // S2
      v4f accr=(v4f){0,0,0,0}, accz=(v4f){0,0,0,0};
      v4f accxn=(v4f){0,0,0,0}, acchn=(v4f){0,0,0,0};
      #pragma unroll
      for (int kb=0;kb<16;kb++){
        v8s af = lds_frag8(abuf + lr*520 + kb*32 + q*8);
        #pragma unroll
        for (int g=0;g<3;g++){
          int i = g*16 + kb;
          v8s b = (i < NL1) ? ldsfrag(wlds, w*NL1 + i, lane) : wreg[i-NL1];
          v4f* A = (g==0)?&accr:(g==1)?&accz:((kb<8)?&accxn:&acchn);
          *A = mfma16(af, b, *A);
        }
      }
      int mk[4];
      #pragma unroll
      for (int rr=0;rr<4;rr++) mk[rr] = maskT[(size_t)s*NB + rowbase + q*4 + rr];
      __syncthreads();                    // S3
      bf16* slot = ring1o + (size_t)(s&1)*RG*128;
      #pragma unroll
      for (int rr=0;rr<4;rr++){
        int row = q*4 + rr;
        float rg = sigm(accr[rr] + birv);
        float zg = sigm(accz[rr] + bizv);
        float nn = tanh_f(accxn[rr] + binv + rg*(acchn[rr]+bhnv));
        float hv = (1.f-zg)*nn + zg*h1a[rr];
        float h2 = mk[rr] ? hv : h1a[rr];
        h1a[rr] = h2;
        int ch_col = w*16 + lr;
        abuf[row*520 + 256 + ch*128 + ch_col] = bf16bits(h2);
        stg_coh_pair(slot + ((size_t)row*128 + (ch_col & ~1)), lr, h2);
        if (s == 127) hTf[(size_t)(rowbase+row)*HE + d] = h2;
      }
      __syncthreads();                    // S4: h1 stores drained
      if (tid == 0) cntset(cXo, s+1);
      // ---- fused MLP (needs h1[:, :128] = ch0's own half, already in abuf) ----
      if (ch == 0 && w == 0){
        int vl = maskT[(size_t)s*NB + rowbase + lr];
        v4f acc[4];
        #pragma unroll
        for (int c=0;c<4;c++) acc[c]=(v4f){0,0,0,0};
        #pragma unroll
        for (int kb=0;kb<4;kb++){
          v8s af = vl ? lds_frag8(abuf + lr*520 + 256 + kb*32 + q*8)
                      : (v8s){0,0,0,0,0,0,0,0};
          #pragma unroll
          for (int c=0;c<4;c++) acc[c] = mfma16(af, ldsfrag(w1s, c*4+kb, lane), acc[c]);
        }
        float* outp = encp + (size_t)s*NB*2;
        #pragma unroll
        for (int rr=0;rr<4;rr++){
          float p0=0.f, p1=0.f;
          #pragma unroll
          for (int c=0;c<4;c++){
            float hv = acc[c][rr] + b1v[c]; hv = hv>0.f ? hv : 0.f;
            p0 += hv*w20[c]; p1 += hv*w21[c];
          }
          #pragma unroll
          for (int m=1;m<16;m<<=1){ p0 += __shfl_xor(p0,m,64); p1 += __shfl_xor(p1,m,64); }
          if (lr == 0){
            int grow = rowbase + q*4 + rr;
            outp[(size_t)grow*2]   = softplusf(p0+b20);
            outp[(size_t)grow*2+1] = softplusf(p1+b21);
          }
        }
      }
    }
  }
}

// ================= decoder: r5 structure, P4 folded into P1 phase (6 -> 5 barriers/iter) =================
__global__ __attribute__((amdgpu_flat_work_group_size(512,512), amdgpu_waves_per_eu(1)))
void k_decoder(char* ws, const void* eps, const void* feat, void* out){
  extern __shared__ __align__(16) char dsm[];
  short* s_h0b = (short*)dsm;                       // [32][HDS]      @0      10496
  short* s_h1b = s_h0b + 32*HDS;                    //                @10496  10496
  float* s_inp = (float*)(dsm + 20992);             // [64]           @20992  256
  float* s_red = (float*)(dsm + 21248);             // [128]          @21248  512
  short* s_wh  = (short*)(dsm + 21760);             // WH1 t0..7 frag @21760  122880
  short* s_cw0 = (short*)(dsm + 144640);            // [3][4][132]    @144640 3168
  short* s_cwx = (short*)(dsm + 147808);            //                        3168
  short* s_cwh = (short*)(dsm + 150976);            //                        3168
  float* s_tail= (float*)(dsm + 154144);            // [512]                  2048
  float* s_th  = (float*)(dsm + 156192);            // [2][32][4]             1024
  float* s_tt0 = (float*)(dsm + 157216);            // [4][10]                160
  float* s_tt1 = (float*)(dsm + 157376);            // [4][4]                 64

  const int isbf = *(const int*)(ws+wsoff::FLAG);
  const int tid = threadIdx.x;
  const int lane = tid & 63, w = tid >> 6, lr = lane & 15, q = lane >> 4;
  const int rowbase = blockIdx.x*32;
  constexpr size_t N0v = (size_t)NS*NB*127*2;

  const bf16* W0g  = bfp(ws,wsoff::WDHH0);
  const bf16* WX1g = bfp(ws,wsoff::WDIH1);

  // ---- phase A: zero + LDS staging ----
  for (int i = tid; i < 2*32*HDS; i += 512) s_h0b[i] = 0;
  {
    const short* src = (const short*)(ws + wsoff::WDHH1);
    for (int idx = tid; idx < 120*512; idx += 512){
      int u = idx >> 9, le = idx & 511, ln = le >> 3, e = le & 7, lrr = ln & 15, qq = ln >> 4;
      int kb = u % 5, t2 = u / 5, cc = t2 & 7, g = t2 >> 3;
      s_wh[idx] = src[(size_t)(g*GDP + cc*16 + lrr)*HDP + kb*32 + qq*8 + e];
    }
    const short* g0 = (const short*)(ws + wsoff::WDHH0);
    const short* gx = (const short*)(ws + wsoff::WDIH1);
    const short* gh = (const short*)(ws + wsoff::WDHH1);
    for (int i = tid; i < 3*4*132; i += 512){
      int k = i % 132, t2 = i / 132, c4 = t2 & 3, g = t2 >> 2;
      size_t so = (size_t)(g*GDP + 128 + c4)*HDP + k;
      s_cw0[i] = g0[so]; s_cwx[i] = gx[so]; s_cwh[i] = gh[so];
    }
  }
  if (tid < 4){
    const float* wih = f32p(ws,wsoff::WDIH0F);
    const float* bi0 = f32p(ws,wsoff::BDIH0); const float* bh0 = f32p(ws,wsoff::BDHH0);
    const float* bi1 = f32p(ws,wsoff::BDIH1); const float* bh1 = f32p(ws,wsoff::BDHH1);
    int dd = 128 + tid;
    float* T = s_tt0 + tid*10;
    T[0]=wih[(0*HD+dd)*2]; T[1]=wih[(0*HD+dd)*2+1];
    T[2]=wih[(1*HD+dd)*2]; T[3]=wih[(1*HD+dd)*2+1];
    T[4]=wih[(2*HD+dd)*2]; T[5]=wih[(2*HD+dd)*2+1];
    T[6]=bi0[dd]+bh0[dd]; T[7]=bi0[HD+dd]+bh0[HD+dd]; T[8]=bi0[2*HD+dd]; T[9]=bh0[2*HD+dd];
    float* T1 = s_tt1 + tid*4;
    T1[0]=bi1[dd]+bh1[dd]; T1[1]=bi1[HD+dd]+bh1[HD+dd]; T1[2]=bi1[2*HD+dd]; T1[3]=bh1[2*HD+dd];
  }
  if (tid < 64){
    int r0 = tid >> 1, c = tid & 1;
    int b = (rowbase + r0) & 1023;
    float v = f32p(ws,wsoff::ENCP)[((size_t)127*NB + b)*2 + c];
    s_inp[tid] = v;
    st_out(out, N0v + ((size_t)(rowbase+r0)*64)*2 + c, v, isbf);
  }
  __syncthreads();

  // ---- phase B: per-thread state init + RF weights ----
  const int d = w*16 + lr;   // always < 128
  float e0a[10], e1a[4];
  {
    const float* wih = f32p(ws,wsoff::WDIH0F);
    const float* bi0 = f32p(ws,wsoff::BDIH0); const float* bh0 = f32p(ws,wsoff::BDHH0);
    const float* bi1 = f32p(ws,wsoff::BDIH1); const float* bh1 = f32p(ws,wsoff::BDHH1);
    e0a[0]=wih[(0*HD+d)*2]; e0a[1]=wih[(0*HD+d)*2+1];
    e0a[2]=wih[(1*HD+d)*2]; e0a[3]=wih[(1*HD+d)*2+1];
    e0a[4]=wih[(2*HD+d)*2]; e0a[5]=wih[(2*HD+d)*2+1];
    e0a[6]=bi0[d]+bh0[d]; e0a[7]=bi0[HD+d]+bh0[HD+d]; e0a[8]=bi0[2*HD+d]; e0a[9]=bh0[2*HD+d];
    e1a[0]=bi1[d]+bh1[d]; e1a[1]=bi1[HD+d]+bh1[HD+d]; e1a[2]=bi1[2*HD+d]; e1a[3]=bh1[2*HD+d];
  }
  float h0a[2][4], h1a[2][4];
  {
    const float* h0T = f32p(ws,wsoff::H0F0);
    const float* h1T = f32p(ws,wsoff::H1F0);
    #pragma unroll
    for (int m=0;m<2;m++)
      #pragma unroll
      for (int r=0;r<4;r++){
        int row = m*16 + q*4 + r, grow = rowbase + row;
        int s = grow >> 10, b = grow & 1023;
        float e0 = ld_any(eps, ((size_t)(s*2+0)*NB + b)*NH + d, isbf);
        float e1 = ld_any(eps, ((size_t)(s*2+1)*NB + b)*NH + d, isbf);
        float v0 = e0*__expf(0.5f*h0T[(size_t)b*HE + NH + d]) + h0T[(size_t)b*HE + d];
        float v1 = e1*__expf(0.5f*h1T[(size_t)b*HE + NH + d]) + h1T[(size_t)b*HE + d];
        h0a[m][r] = v0; h1a[m][r] = v1;
        s_h0b[row*HDS + d] = bf16bits(v0);
        s_h1b[row*HDS + d] = bf16bits(v1);
      }
  }
  if (tid < 128){
    int c4 = tid >> 5, row = tid & 31;
    int b = (rowbase + row) & 1023;
    float fc = ld_any(feat, (size_t)b*3072 + 2048 + c4, isbf);
    s_th[row*4 + c4] = fc;
    s_th[128 + row*4 + c4] = fc;
    s_h0b[row*HDS + 128 + c4] = bf16bits(fc);
    s_h1b[row*HDS + 128 + c4] = bf16bits(fc);
  }
  v8s w0f[3][5], wxf[3][5];
  #pragma unroll
  for (int g=0;g<3;g++)
    #pragma unroll
    for (int kb=0;kb<5;kb++){
      size_t off = (size_t)(g*GDP + w*16 + lr)*HDP + kb*32 + q*8;
      w0f[g][kb] = fragld(W0g, off);
      wxf[g][kb] = fragld(WX1g, off);
    }
  v8s w1f[2][4]; float b1v[2], w20v[2], w21v[2];
  if (w == 5 || w == 6){
    const int tb = (w-5)*2;
    const bf16* W1g = bfp(ws,wsoff::W1B);
    #pragma unroll
    for (int ct=0;ct<2;ct++){
      #pragma unroll
      for (int kb=0;kb<4;kb++)
        w1f[ct][kb] = fragld(W1g, (size_t)((tb+ct)*16+lr)*NH + kb*32 + q*8);
      b1v[ct]  = f32p(ws,wsoff::B1F)[(tb+ct)*16+lr];
      w20v[ct] = f32p(ws,wsoff::W2F)[(tb+ct)*16+lr];
      w21v[ct] = f32p(ws,wsoff::W2F)[64+(tb+ct)*16+lr];
    }
  }
  const float b20 = f32p(ws,wsoff::B2F)[0], b21 = f32p(ws,wsoff::B2F)[1];
  __syncthreads();

  const int ttg = tid >> 7, ttc4 = (tid >> 5) & 3, ttrow = tid & 31;
  for (int k = 0; k < 63; ++k){
    // ---- P1: main MFMA + tail dots + (k>=1: P4 combine -> s_inp, store out[k]) ----
    v4f p1[3][2];
    #pragma unroll
    for (int g=0;g<3;g++){ p1[g][0]=(v4f){0,0,0,0}; p1[g][1]=(v4f){0,0,0,0}; }
    #pragma unroll
    for (int m=0;m<2;m++)
      #pragma unroll
      for (int kb=0;kb<5;kb++){
        v8s A = lds_frag8(s_h0b + (m*16+lr)*HDS + kb*32 + q*8);
        #pragma unroll
        for (int g=0;g<3;g++) p1[g][m] = mfma16(A, w0f[g][kb], p1[g][m]);
      }
    if (k >= 1 && tid < 64){
      int row = tid >> 1, c = tid & 1;
      float p = s_red[row*2 + c] + s_red[64 + row*2 + c];
      float v = softplusf(p + (c ? b21 : b20));
      s_inp[tid] = v;
      st_out(out, N0v + ((size_t)(rowbase+row)*64 + k)*2 + c, v, isbf);
    }
    if (tid < 384){
      const unsigned* st = (const unsigned*)s_h0b + ttrow*(HDS/2);
      const unsigned* wp = (const unsigned*)s_cw0 + (ttg*4+ttc4)*66;
      float t0=0.f, t1=0.f, t2v=0.f, t3v=0.f;
      #pragma unroll 2
      for (int k2 = 0; k2 < 64; k2 += 4){
        unsigned sa=st[k2],   wa=wp[k2];
        unsigned sb=st[k2+1], wb=wp[k2+1];
        unsigned sc=st[k2+2], wc=wp[k2+2];
        unsigned sd=st[k2+3], wd=wp[k2+3];
        t0  += uasf(sa<<16)*uasf(wa<<16) + uasf(sa & 0xffff0000u)*uasf(wa & 0xffff0000u);
        t1  += uasf(sb<<16)*uasf(wb<<16) + uasf(sb & 0xffff0000u)*uasf(wb & 0xffff0000u);
        t2v += uasf(sc<<16)*uasf(wc<<16) + uasf(sc & 0xffff0000u)*uasf(wc & 0xffff0000u);
        t3v += uasf(sd<<16)*uasf(wd<<16) + uasf(sd & 0xffff0000u)*uasf(wd & 0xffff0000u);
      }
      { unsigned sa=st[64], wa=wp[64], sb=st[65], wb=wp[65];
        t0 += uasf(sa<<16)*uasf(wa<<16) + uasf(sa & 0xffff0000u)*uasf(wa & 0xffff0000u);
        t1 += uasf(sb<<16)*uasf(wb<<16) + uasf(sb & 0xffff0000u)*uasf(wb & 0xffff0000u); }
      s_tail[(ttg*4+ttc4)*32 + ttrow] = (t0+t1)+(t2v+t3v);
    }
    __syncthreads();
    // ---- P1 epilogue (write s_h0b new) ----
    #pragma unroll
    for (int m=0;m<2;m++)
      #pragma unroll
      for (int r=0;r<4;r++){
        int row = m*16 + q*4 + r;
        float i0 = s_inp[row*2], i1 = s_inp[row*2+1];
        float rr = sigm(i0*e0a[0]+i1*e0a[1] + p1[0][m][r] + e0a[6]);
        float zz = sigm(i0*e0a[2]+i1*e0a[3] + p1[1][m][r] + e0a[7]);
        float nn = tanh_f(i0*e0a[4]+i1*e0a[5] + e0a[8] + rr*(p1[2][m][r] + e0a[9]));
        float h = (1.f-zz)*nn + zz*h0a[m][r];
        h0a[m][r] = h;
        s_h0b[row*HDS + d] = bf16bits(h);
      }
    if (tid < 128){
      int c4 = tid >> 5, row = tid & 31;
      float ar = s_tail[(0*4+c4)*32+row], az = s_tail[(1*4+c4)*32+row], an = s_tail[(2*4+c4)*32+row];
      const float* T = s_tt0 + c4*10;
      float i0 = s_inp[row*2], i1 = s_inp[row*2+1];
      float rr = sigm(i0*T[0]+i1*T[1] + ar + T[6]);
      float zz = sigm(i0*T[2]+i1*T[3] + az + T[7]);
      float nn = tanh_f(i0*T[4]+i1*T[5] + T[8] + rr*(an + T[9]));
      float ho = s_th[row*4 + c4];
      float h = (1.f-zz)*nn + zz*ho;
      s_th[row*4 + c4] = h;
      s_h0b[row*HDS + 128 + c4] = bf16bits(h);
    }
    __syncthreads();
    // ---- P2: main MFMA + tail dots (read s_h0b new, s_h1b old) ----
    v4f p2[4][2];
    #pragma unroll
    for (int g=0;g<4;g++){ p2[g][0]=(v4f){0,0,0,0}; p2[g][1]=(v4f){0,0,0,0}; }
    #pragma unroll
    for (int m=0;m<2;m++)
      #pragma unroll
      for (int kb=0;kb<5;kb++){
        v8s ax = lds_frag8(s_h0b + (m*16+lr)*HDS + kb*32 + q*8);
        v8s ah = lds_frag8(s_h1b + (m*16+lr)*HDS + kb*32 + q*8);
        #pragma unroll
        for (int g=0;g<3;g++){
          int aix = (g==2) ? 2 : g, aih = (g==2) ? 3 : g;
          p2[aix][m] = mfma16(ax, wxf[g][kb], p2[aix][m]);
          p2[aih][m] = mfma16(ah, ldsfrag(s_wh, (g*8+w)*5 + kb, lane), p2[aih][m]);
        }
      }
    {
      const unsigned* h0p = (const unsigned*)s_h0b + ttrow*(HDS/2);
      const unsigned* h1p = (const unsigned*)s_h1b + ttrow*(HDS/2);
      float td = 0.f;
      if (ttg <= 1){
        const unsigned* wx = (const unsigned*)s_cwx + (ttg*4+ttc4)*66;
        const unsigned* wh = (const unsigned*)s_cwh + (ttg*4+ttc4)*66;
        float x0=0.f, x1=0.f, y0=0.f, y1=0.f;
        #pragma unroll 2
        for (int k2 = 0; k2 < 66; k2 += 2){
          unsigned sa=h0p[k2],   wa=wx[k2];
          unsigned sb=h0p[k2+1], wb=wx[k2+1];
          unsigned ha=h1p[k2],   va=wh[k2];
          unsigned hb=h1p[k2+1], vb=wh[k2+1];
          x0 += uasf(sa<<16)*uasf(wa<<16) + uasf(sa & 0xffff0000u)*uasf(wa & 0xffff0000u);
          x1 += uasf(sb<<16)*uasf(wb<<16) + uasf(sb & 0xffff0000u)*uasf(wb & 0xffff0000u);
          y0 += uasf(ha<<16)*uasf(va<<16) + uasf(ha & 0xffff0000u)*uasf(va & 0xffff0000u);
          y1 += uasf(hb<<16)*uasf(vb<<16) + uasf(hb & 0xffff0000u)*uasf(vb & 0xffff0000u);
        }
        td = (x0+x1)+(y0+y1);
      } else if (ttg == 2){
        const unsigned* wx = (const unsigned*)s_cwx + (2*4+ttc4)*66;
        float x0=0.f, x1=0.f;
        #pragma unroll 2
        for (int k2 = 0; k2 < 66; k2 += 2){
          unsigned sa=h0p[k2], wa=wx[k2], sb=h0p[k2+1], wb=wx[k2+1];
          x0 += uasf(sa<<16)*uasf(wa<<16) + uasf(sa & 0xffff0000u)*uasf(wa & 0xffff0000u);
          x1 += uasf(sb<<16)*uasf(wb<<16) + uasf(sb & 0xffff0000u)*uasf(wb & 0xffff0000u);
        }
        td = x0+x1;
      } else {
        const unsigned* wh = (const unsigned*)s_cwh + (2*4+ttc4)*66;
        float y0=0.f, y1=0.f;
        #pragma unroll 2
        for (int k2 = 0; k2 < 66; k2 += 2){
          unsigned sa=h1p[k2], wa=wh[k2], sb=h1p[k2+1], wb=wh[k2+1];
          y0 += uasf(sa<<16)*uasf(wa<<16) + uasf(sa & 0xffff0000u)*uasf(wa & 0xffff0000u);
          y1 += uasf(sb<<16)*uasf(wb<<16) + uasf(sb & 0xffff0000u)*uasf(wb & 0xffff0000u);
        }
        td = y0+y1;
      }
      s_tail[(ttg*4+ttc4)*32 + ttrow] = td;
    }
    __syncthreads();
    // ---- P2 epilogue (write s_h1b new) ----
    #pragma unroll
    for (int m=0;m<2;m++)
      #pragma unroll
      for (int r=0;r<4;r++){
        int row = m*16 + q*4 + r;
        float rr = sigm(p2[0][m][r] + e1a[0]);
        float zz = sigm(p2[1][m][r] + e1a[1]);
        float nn = tanh_f(p2[2][m][r] + e1a[2] + rr*(p2[3][m][r] + e1a[3]));
        float h = (1.f-zz)*nn + zz*h1a[m][r];
        h1a[m][r] = h;
        s_h1b[row*HDS + d] = bf16bits(h);
      }
    if (tid < 128){
      int c4 = tid >> 5, row = tid & 31;
      float tr = s_tail[(0*4+c4)*32+row], tz = s_tail[(1*4+c4)*32+row];
      float txn = s_tail[(2*4+c4)*32+row], thn = s_tail[(3*4+c4)*32+row];
      const float* T1 = s_tt1 + c4*4;
      float rr = sigm(tr + T1[0]);
      float zz = sigm(tz + T1[1]);
      float nn = tanh_f(txn + T1[2] + rr*(thn + T1[3]));
      float ho = s_th[128 + row*4 + c4];
      float h = (1.f-zz)*nn + zz*ho;
      s_th[128 + row*4 + c4] = h;
      s_h1b[row*HDS + 128 + c4] = bf16bits(h);
    }
    __syncthreads();
    // ---- P3: MLP halves on waves 5,6 ----
    if (w == 5 || w == 6){
      v4f a3[2][2];
      #pragma unroll
      for (int ct=0;ct<2;ct++){ a3[ct][0]=(v4f){0,0,0,0}; a3[ct][1]=(v4f){0,0,0,0}; }
      #pragma unroll
      for (int m=0;m<2;m++)
        #pragma unroll
        for (int kb=0;kb<4;kb++){
          v8s A = lds_frag8(s_h1b + (m*16+lr)*HDS + kb*32 + q*8);
          #pragma unroll
          for (int ct=0;ct<2;ct++) a3[ct][m] = mfma16(A, w1f[ct][kb], a3[ct][m]);
        }
      #pragma unroll
      for (int m=0;m<2;m++)
        #pragma unroll
        for (int r=0;r<4;r++){
          float p0 = 0.f, p1v = 0.f;
          #pragma unroll
          for (int ct=0;ct<2;ct++){
            float hv = a3[ct][m][r] + b1v[ct]; hv = hv > 0.f ? hv : 0.f;
            p0 += hv*w20v[ct]; p1v += hv*w21v[ct];
          }
          #pragma unroll
          for (int mm=1;mm<16;mm<<=1){ p0 += __shfl_xor(p0,mm,64); p1v += __shfl_xor(p1v,mm,64); }
          if (lr == 0){
            int row = m*16 + q*4 + r;
            s_red[(w-5)*64 + row*2]   = p0;
            s_red[(w-5)*64 + row*2+1] = p1v;
          }
        }
    }
    __syncthreads();
  }
  // ---- final combine: out[63] (uses s_red from last P3) ----
  if (tid < 64){
    int row = tid >> 1, c = tid & 1;
    float p = s_red[row*2 + c] + s_red[64 + row*2 + c];
    float v = softplusf(p + (c ? b21 : b20));
    st_out(out, N0v + ((size_t)(rowbase+row)*64 + 63)*2 + c, v, isbf);
  }
}

// ---------- encoder-part output assembly ----------
__global__ void k_assemble_enc(char* ws, void* out){
  int isbf = *(const int*)(ws+wsoff::FLAG);
  const float* encp = f32p(ws,wsoff::ENCP);
  constexpr size_t N0v = (size_t)NS*NB*127*2;
  for (size_t i = (size_t)blockIdx.x*blockDim.x + threadIdx.x; i < N0v;
       i += (size_t)gridDim.x*blockDim.x){
    int c = (int)(i & 1); size_t qq = i >> 1;
    int tt = (int)(qq % 127); size_t q2 = qq / 127; int b = (int)(q2 & 1023);
    st_out(out, i, encp[((size_t)tt*NB + b)*2 + c], isbf);
  }
}

extern "C" void kernel_launch(void* const* d_in, const int* in_sizes, int n_in,
                              void* d_out, int out_size, void* d_ws, size_t ws_size,
                              hipStream_t stream) {
  char* ws = (char*)d_ws;
  const int* mask = (const int*)d_in[2];
  auto gb = [](size_t n){ return dim3((unsigned)((n + 255)/256)); };

  hipMemsetAsync(ws+wsoff::CNT, 0, 192*64, stream);

  k_detect<<<1,64,0,stream>>>(ws, d_in[3]);

  k_stage_xs   <<<gb((size_t)NT*NB*KX),256,0,stream>>>(ws, d_in[0], d_in[1]);
  k_stage_maskT<<<gb((size_t)NT*NB),256,0,stream>>>(ws, mask);
  k_stage_pad<<<gb(768*32) ,256,0,stream>>>(ws, d_in[7],  wsoff::WIH0, 768, 18, 32);
  k_stage_pad<<<gb(768*256),256,0,stream>>>(ws, d_in[8],  wsoff::WHH0, 768, 256, 256);
  k_stage_pad<<<gb(768*256),256,0,stream>>>(ws, d_in[11], wsoff::WIH1, 768, 256, 256);
  k_stage_pad<<<gb(768*256),256,0,stream>>>(ws, d_in[12], wsoff::WHH1, 768, 256, 256);
  k_stage_pad<<<gb(64*128) ,256,0,stream>>>(ws, d_in[23], wsoff::W1B,  64, 128, 128);
  k_stage_dec<<<gb(432*HDP),256,0,stream>>>(ws, d_in[16], wsoff::WDHH0);
  k_stage_dec<<<gb(432*HDP),256,0,stream>>>(ws, d_in[19], wsoff::WDIH1);
  k_stage_dec<<<gb(432*HDP),256,0,stream>>>(ws, d_in[20], wsoff::WDHH1);

  SmallSegs ss;
  const void* srcs[12] = {d_in[9],d_in[10],d_in[13],d_in[14],d_in[15],
                          d_in[17],d_in[18],d_in[21],d_in[22],
                          d_in[24],d_in[25],d_in[26]};
  const size_t offs[12] = {wsoff::BIH0,wsoff::BHH0,wsoff::BIH1,wsoff::BHH1,wsoff::WDIH0F,
                           wsoff::BDIH0,wsoff::BDHH0,wsoff::BDIH1,wsoff::BDHH1,
                           wsoff::B1F,wsoff::W2F,wsoff::B2F};
  const int ns[12] = {768,768,768,768,792,396,396,396,396,64,128,2};
  for (int i=0;i<12;i++){ ss.src[i]=srcs[i]; ss.dstoff[i]=(int)offs[i]; ss.n[i]=ns[i]; }
  k_stage_small<<<12,256,0,stream>>>(ws, ss);

  hipFuncSetAttribute(reinterpret_cast<const void*>(k_encoder),
                      hipFuncAttributeMaxDynamicSharedMemorySize, ENC_LDS);
  hipFuncSetAttribute(reinterpret_cast<const void*>(k_decoder),
                      hipFuncAttributeMaxDynamicSharedMemorySize, 157440);

  k_encoder<<<192,512,ENC_LDS,stream>>>(ws);
  k_decoder<<<256,512,157440,stream>>>(ws, d_in[3], d_in[1], d_out);
  k_assemble_enc<<<2048,256,0,stream>>>(ws, d_out);
}

// Round 11
// 1783.833 us; speedup vs baseline: 1.2808x; 1.0196x over previous
//
#include <hip/hip_runtime.h>
#include <hip/hip_bf16.h>
#include <math.h>

typedef __hip_bfloat16 bf16;
typedef short v8s __attribute__((ext_vector_type(8)));
typedef float v4f __attribute__((ext_vector_type(4)));

#define NB   1024
#define NT   128
#define NH   128
#define HE   256
#define HD   132
#define HDP  160
#define HDS  164
#define GDP  144
#define NS   8
#define KX   32
#define RG   16          // batch rows per encoder row-group
#define NRG  64          // row groups (64*16 = 1024)

namespace wsoff {
constexpr size_t al(size_t x){ return (x + 255) & ~size_t(255); }
constexpr size_t FLAG  = 0;
constexpr size_t CNT   = 256;                  // 192 counters x 64B
constexpr size_t XS    = al(CNT + 192*64);
constexpr size_t MASKT = al(XS    + (size_t)NT*NB*KX*2);   // int32 [NT][NB]
constexpr size_t WIH0  = al(MASKT + (size_t)NT*NB*4);
constexpr size_t WHH0  = al(WIH0  + 768*32*2);
constexpr size_t WIH1  = al(WHH0  + 768*256*2);
constexpr size_t WHH1  = al(WIH1  + 768*256*2);
constexpr size_t BIH0  = al(WHH1  + 768*256*2);
constexpr size_t BHH0  = al(BIH0  + 768*4);
constexpr size_t BIH1  = al(BHH0  + 768*4);
constexpr size_t BHH1  = al(BIH1  + 768*4);
constexpr size_t WDHH0 = al(BHH1  + 768*4);
constexpr size_t WDIH1 = al(WDHH0 + 432*HDP*2);
constexpr size_t WDHH1 = al(WDIH1 + 432*HDP*2);
constexpr size_t WDIH0F= al(WDHH1 + 432*HDP*2);
constexpr size_t BDIH0 = al(WDIH0F+ 792*4);
constexpr size_t BDHH0 = al(BDIH0 + 396*4);
constexpr size_t BDIH1 = al(BDHH0 + 396*4);
constexpr size_t BDHH1 = al(BDIH1 + 396*4);
constexpr size_t W1B   = al(BDHH1 + 396*4);
constexpr size_t B1F   = al(W1B   + 64*128*2);
constexpr size_t W2F   = al(B1F   + 64*4);
constexpr size_t B2F   = al(W2F   + 128*4);
constexpr size_t H0F0  = al(B2F   + 2*4);
constexpr size_t H1F0  = al(H0F0  + (size_t)NB*HE*4);
constexpr size_t RING0 = al(H1F0  + (size_t)NB*HE*4);          // 64 grp x 4 slot x 16x256 bf16
constexpr size_t RING1 = al(RING0 + (size_t)NRG*4*RG*256*2);   // 128 slots (rb*2+ch) x 2 x 16x128 bf16
constexpr size_t ENCP  = al(RING1 + (size_t)128*2*RG*128*2);
}

// ---------- helpers ----------
__device__ __forceinline__ float ld_any(const void* p, size_t i, int isbf){
  return isbf ? __bfloat162float(((const bf16*)p)[i]) : ((const float*)p)[i];
}
__device__ __forceinline__ void st_out(void* out, size_t i, float v, int isbf){
  if (isbf) ((bf16*)out)[i] = __float2bfloat16(v); else ((float*)out)[i] = v;
}
__device__ __forceinline__ float sigm(float x){ return 1.0f/(1.0f + __expf(-x)); }
__device__ __forceinline__ float tanh_f(float x){
  float t = __expf(2.0f*x); return 1.0f - 2.0f/(t+1.0f);
}
__device__ __forceinline__ float softplusf(float x){ return x>20.f ? x : log1pf(__expf(x)); }
__device__ __forceinline__ v4f mfma16(v8s a, v8s b, v4f c){
  return __builtin_amdgcn_mfma_f32_16x16x32_bf16(a,b,c,0,0,0);
}
__device__ __forceinline__ v8s fragld(const bf16* base, size_t elem_off){
  return *reinterpret_cast<const v8s*>(base + elem_off);
}
__device__ __forceinline__ v8s ldsfrag(const short* sm, int unit, int lane){
  return *reinterpret_cast<const v8s*>(sm + (unit<<9) + (lane<<3));
}
__device__ __forceinline__ v8s lds_frag8(const short* p){
  union { long long l[2]; v8s s; } r;
  r.l[0] = *(const long long*)(p);
  r.l[1] = *(const long long*)(p + 4);
  return r.s;
}
__device__ __forceinline__ short bf16bits(float v){
  bf16 h = __float2bfloat16(v); short s; __builtin_memcpy(&s,&h,2); return s;
}
__device__ __forceinline__ float uasf(unsigned u){ float f; __builtin_memcpy(&f,&u,4); return f; }
// packed bf16 dot: d = a.lo*b.lo + a.hi*b.hi + c  (V_DOT2_F32_BF16, VOP3P)
__device__ __forceinline__ float dot2bf(unsigned a, unsigned b, float c){
  float d;
  asm volatile("v_dot2_f32_bf16 %0, %1, %2, %3" : "=v"(d) : "v"(a), "v"(b), "v"(c));
  return d;
}
__device__ __forceinline__ v8s ldg_coh16(const bf16* p){
  union { unsigned long long u[2]; v8s s; } r;
  const unsigned long long* q = (const unsigned long long*)p;
  r.u[0] = __hip_atomic_load(q+0, __ATOMIC_RELAXED, __HIP_MEMORY_SCOPE_AGENT);
  r.u[1] = __hip_atomic_load(q+1, __ATOMIC_RELAXED, __HIP_MEMORY_SCOPE_AGENT);
  return r.s;
}
__device__ __forceinline__ void stg_coh_pair(bf16* base_even, int lr, float v){
  bf16 h = __float2bfloat16(v);
  unsigned vv; { unsigned short b; __builtin_memcpy(&b, &h, 2); vv = b; }
  unsigned ov = (unsigned)__shfl_xor((int)vv, 1, 64);
  if (!(lr & 1))
    __hip_atomic_store((unsigned*)base_even, vv | (ov<<16), __ATOMIC_RELAXED, __HIP_MEMORY_SCOPE_AGENT);
}
__device__ __forceinline__ float*  f32p(char* ws, size_t off){ return (float*)(ws+off); }
__device__ __forceinline__ bf16*   bfp (char* ws, size_t off){ return (bf16*)(ws+off); }

// ---------- counters ----------
__device__ __forceinline__ int* cntp(char* ws, int idx){
  return (int*)(ws + wsoff::CNT + (size_t)idx*64);
}
__device__ __forceinline__ void pollge(int* f, int v){
  while (__hip_atomic_load(f, __ATOMIC_RELAXED, __HIP_MEMORY_SCOPE_AGENT) < v)
    __builtin_amdgcn_s_sleep(1);
}
__device__ __forceinline__ void cntset(int* f, int v){
  __hip_atomic_store(f, v, __ATOMIC_RELAXED, __HIP_MEMORY_SCOPE_AGENT);
}

// ---------- dtype detection ----------
__global__ void k_detect(char* ws, const void* eps){
  const unsigned short* p = (const unsigned short*)eps;
  int lane = threadIdx.x;
  unsigned short u = p[2*lane];
  int e = (u>>7)&0xFF;
  bool pl = (e>=118 && e<=130);
  unsigned long long m = __ballot(pl);
  if (lane==0) *(int*)(ws+wsoff::FLAG) = (__popcll(m) >= 32) ? 1 : 0;
}

// ---------- staging ----------
__global__ void k_stage_xs(char* ws, const void* x, const void* feat){
  int isbf = *(const int*)(ws+wsoff::FLAG);
  size_t i = (size_t)blockIdx.x*blockDim.x + threadIdx.x;
  if (i >= (size_t)NT*NB*KX) return;
  int c = i % KX; size_t q = i / KX; int b = q % NB; int t = q / NB;
  float v = 0.f;
  if (c < 2)        v = ld_any(x,    ((size_t)b*NT + t)*2 + c, isbf);
  else if (c < 18)  v = ld_any(feat, ((size_t)b*192 + t)*16 + (c-2), isbf);
  ((bf16*)(ws+wsoff::XS))[i] = __float2bfloat16(v);
}
__global__ void k_stage_maskT(char* ws, const int* mask){
  size_t i = (size_t)blockIdx.x*blockDim.x + threadIdx.x;
  if (i >= (size_t)NT*NB) return;
  int b = i % NB, t = i / NB;
  ((int*)(ws+wsoff::MASKT))[i] = mask[(size_t)b*NT + t];
}
__global__ void k_stage_pad(char* ws, const void* src, size_t dstoff, int R, int SC, int DC){
  int isbf = *(const int*)(ws+wsoff::FLAG);
  size_t i = (size_t)blockIdx.x*blockDim.x + threadIdx.x;
  if (i >= (size_t)R*DC) return;
  int r = i / DC, c = i % DC;
  float v = (c < SC) ? ld_any(src, (size_t)r*SC + c, isbf) : 0.f;
  ((bf16*)(ws+dstoff))[i] = __float2bfloat16(v);
}
__global__ void k_stage_dec(char* ws, const void* src, size_t dstoff){
  int isbf = *(const int*)(ws+wsoff::FLAG);
  size_t i = (size_t)blockIdx.x*blockDim.x + threadIdx.x;
  if (i >= (size_t)432*HDP) return;
  int R = i / HDP, c = i % HDP;
  int g = R / GDP, ii = R % GDP;
  float v = (ii < HD && c < HD) ? ld_any(src, ((size_t)(g*HD+ii))*HD + c, isbf) : 0.f;
  ((bf16*)(ws+dstoff))[i] = __float2bfloat16(v);
}
struct SmallSegs { const void* src[12]; int dstoff[12]; int n[12]; };
__global__ void k_stage_small(char* ws, SmallSegs segs){
  int isbf = *(const int*)(ws+wsoff::FLAG);
  int s = blockIdx.x;
  float* dst = (float*)(ws + (size_t)segs.dstoff[s]);
  for (int i = threadIdx.x; i < segs.n[s]; i += blockDim.x)
    dst[i] = ld_any(segs.src[s], i, isbf);
}

// ================= persistent encoder: row-ownership, weights resident per CU =================
// XCD-aware pairing (r9); per-thread polls at point of use (r10).
#define ENC_LDS 156928
__global__ __attribute__((amdgpu_flat_work_group_size(512,512), amdgpu_waves_per_eu(1)))
void k_encoder(char* ws){
  extern __shared__ __align__(16) char smem[];
  const int bid = blockIdx.x, tid = threadIdx.x;
  const int lane = tid & 63, w = tid >> 6, lr = lane & 15, q = lane >> 4;
  const int* maskT = (const int*)(ws + wsoff::MASKT);

  if (bid < NRG){
    // ---------------- LAYER 0 ----------------
    constexpr int NL0 = 18;              // LDS weight tiles per wave (of 54)
    constexpr int NR0 = 54 - NL0;        // 36 register tiles (144 VGPR)
    const int rb = bid, rowbase = rb*RG;
    short* wlds = (short*)smem;                     // 8*18 KB
    short* abuf = (short*)(smem + 8*NL0*1024);      // [16][296] bf16: k = 256 h | 32 x | 8 pad
    int* cL0 = cntp(ws, rb);
    int* cXa = cntp(ws, NRG + rb*2);
    int* cXb = cntp(ws, NRG + rb*2 + 1);
    const short* WH = (const short*)(ws + wsoff::WHH0);
    const short* WI = (const short*)(ws + wsoff::WIH0);
    for (int idx = tid; idx < 8*NL0*512; idx += 512){
      int slot = idx >> 9, le = idx & 511, ln = le >> 3, j = le & 7, lrr = ln & 15, qq = ln >> 4;
      int w2 = slot / NL0, i = slot % NL0;
      int kb = i % 9, t2 = i / 9, g = t2 % 3, cs = t2 / 3;
      int row = g*HE + w2*32 + cs*16 + lrr;
      wlds[idx] = (kb < 8) ? WH[(size_t)row*256 + kb*32 + qq*8 + j]
                           : WI[(size_t)row*32  + qq*8 + j];
    }
    for (int idx = tid; idx < RG*296; idx += 512) abuf[idx] = 0;
    v8s wreg[NR0];
    #pragma unroll
    for (int i = NL0; i < 54; ++i){
      int kb = i % 9, t2 = i / 9, g = t2 % 3, cs = t2 / 3;
      int row = g*HE + w*32 + cs*16 + lr;
      wreg[i-NL0] = (kb < 8) ? fragld(bfp(ws,wsoff::WHH0), (size_t)row*256 + kb*32 + q*8)
                             : fragld(bfp(ws,wsoff::WIH0), (size_t)row*32 + q*8);
    }
    const float* bih = f32p(ws,wsoff::BIH0);
    const float* bhh = f32p(ws,wsoff::BHH0);
    float birv[2], bizv[2], binv[2], bhnv[2];
    #pragma unroll
    for (int cs=0;cs<2;cs++){
      int d = w*32 + cs*16 + lr;
      birv[cs]=bih[d]+bhh[d]; bizv[cs]=bih[HE+d]+bhh[HE+d];
      binv[cs]=bih[2*HE+d];   bhnv[cs]=bhh[2*HE+d];
    }
    float h0a[2][4] = {};
    float* hTf = f32p(ws, wsoff::H0F0);
    bf16* ring0 = bfp(ws, wsoff::RING0) + (size_t)rb*4*RG*256;
    const bf16* Xs = bfp(ws,wsoff::XS);
    __syncthreads();
    for (int t = 0; t < 128; ++t){
      if (tid < 64){                    // stage x[t] into abuf k 256..287
        int row = tid >> 2, ck = tid & 3;
        v8s xv = fragld(Xs, ((size_t)t*NB + rowbase + row)*KX + ck*8);
        *(v8s*)(abuf + row*296 + 256 + ck*8) = xv;
      }
      __syncthreads();                  // S2
      v4f accr[2], accz[2], accxn[2], acchn[2];
      #pragma unroll
      for (int cs=0;cs<2;cs++){
        accr[cs]=(v4f){0,0,0,0}; accz[cs]=(v4f){0,0,0,0};
        accxn[cs]=(v4f){0,0,0,0}; acchn[cs]=(v4f){0,0,0,0};
      }
      #pragma unroll
      for (int kb=0;kb<9;kb++){
        v8s af = lds_frag8(abuf + lr*296 + kb*32 + q*8);
        #pragma unroll
        for (int cs=0;cs<2;cs++)
          #pragma unroll
          for (int g=0;g<3;g++){
            int i = (cs*3+g)*9 + kb;
            v8s b = (i < NL0) ? ldsfrag(wlds, w*NL0 + i, lane) : wreg[i-NL0];
            v4f* A = (g==0)?&accr[cs]:(g==1)?&accz[cs]:((kb<8)?&acchn[cs]:&accxn[cs]);
            *A = mfma16(af, b, *A);
          }
      }
      int mk[4];
      #pragma unroll
      for (int rr=0;rr<4;rr++) mk[rr] = maskT[(size_t)t*NB + rowbase + q*4 + rr];
      __syncthreads();                  // S3: all A reads done -> safe to overwrite h
      if (t >= 4){                      // ring0 depth-4 back-pressure, per-thread
        pollge(cXa, t-3); pollge(cXb, t-3);
      }
      bf16* slot = ring0 + (size_t)(t&3)*RG*256;
      #pragma unroll
      for (int cs=0;cs<2;cs++){
        int d = w*32 + cs*16 + lr;
        #pragma unroll
        for (int rr=0;rr<4;rr++){
          int row = q*4 + rr;
          float rg = sigm(accr[cs][rr] + birv[cs]);
          float zg = sigm(accz[cs][rr] + bizv[cs]);
          float nn = tanh_f(accxn[cs][rr] + binv[cs] + rg*(acchn[cs][rr]+bhnv[cs]));
          float hv = (1.f-zg)*nn + zg*h0a[cs][rr];
          float h2 = mk[rr] ? hv : h0a[cs][rr];
          h0a[cs][rr] = h2;
          abuf[row*296 + d] = bf16bits(h2);
          stg_coh_pair(slot + ((size_t)row*256 + (d & ~1)), lr, h2);
          if (t == 127) hTf[(size_t)(rowbase+row)*HE + d] = h2;
        }
      }
      __syncthreads();                  // S4: ring stores drained (vmcnt0 per thread)
      if (tid == 0) cntset(cL0, t+1);
    }
  } else {
    // ---------------- LAYER 1 (+ fused MLP on col-half 0) ----------------
    constexpr int NL1 = 15;              // LDS weight tiles per wave (of 48)
    constexpr int NR1 = 48 - NL1;        // 33 register tiles (132 VGPR)
    const int id = bid - NRG;
    const int grp = id >> 4, slot15 = id & 15;
    const int ch = slot15 >> 3, rb = grp*8 + (slot15 & 7);
    const int rowbase = rb*RG;
    short* wlds = (short*)smem;                                 // 8*15 KB
    short* abuf = (short*)(smem + 8*NL1*1024);                  // [16][520]: k = 256 h0 | 256 h1 | 8 pad
    short* w1s  = (short*)(smem + 8*NL1*1024 + RG*520*2);       // MLP W1 tiles, 16KB (ch0 only)
    int* cL0 = cntp(ws, rb);
    int* cXo = cntp(ws, NRG + rb*2 + ch);
    int* cXp = cntp(ws, NRG + rb*2 + (ch^1));
    const short* WX = (const short*)(ws + wsoff::WIH1);
    const short* WHs= (const short*)(ws + wsoff::WHH1);
    for (int idx = tid; idx < 8*NL1*512; idx += 512){
      int slot = idx >> 9, le = idx & 511, ln = le >> 3, j = le & 7, lrr = ln & 15, qq = ln >> 4;
      int w2 = slot / NL1, i = slot % NL1;
      int kb = i & 15, g = i >> 4;
      int row = g*HE + ch*128 + w2*16 + lrr;
      wlds[idx] = (kb < 8) ? WX [(size_t)row*256 + kb*32 + qq*8 + j]
                           : WHs[(size_t)row*256 + (kb-8)*32 + qq*8 + j];
    }
    if (ch == 0){
      const short* W1s = (const short*)(ws + wsoff::W1B);
      for (int idx = tid; idx < 16*512; idx += 512){
        int u = idx >> 9, le = idx & 511, ln = le >> 3, j = le & 7, lrr = ln & 15, qq = ln >> 4;
        int c = u >> 2, kb = u & 3;
        w1s[idx] = W1s[(size_t)(c*16 + lrr)*NH + kb*32 + qq*8 + j];
      }
    }
    for (int idx = tid; idx < RG*520; idx += 512) abuf[idx] = 0;
    v8s wreg[NR1];
    #pragma unroll
    for (int i = NL1; i < 48; ++i){
      int kb = i & 15, g = i >> 4;
      int row = g*HE + ch*128 + w*16 + lr;
      wreg[i-NL1] = (kb < 8) ? fragld(bfp(ws,wsoff::WIH1), (size_t)row*256 + kb*32 + q*8)
                             : fragld(bfp(ws,wsoff::WHH1), (size_t)row*256 + (kb-8)*32 + q*8);
    }
    const float* bih = f32p(ws,wsoff::BIH1);
    const float* bhh = f32p(ws,wsoff::BHH1);
    const int d = ch*128 + w*16 + lr;
    const float birv=bih[d]+bhh[d], bizv=bih[HE+d]+bhh[HE+d];
    const float binv=bih[2*HE+d],   bhnv=bhh[2*HE+d];
    float h1a[4] = {};
    float b1v[4], w20[4], w21[4];
    #pragma unroll
    for (int c=0;c<4;c++){
      int col=c*16+lr;
      b1v[c]=f32p(ws,wsoff::B1F)[col];
      w20[c]=f32p(ws,wsoff::W2F)[col]; w21[c]=f32p(ws,wsoff::W2F)[64+col];
    }
    const float b20 = f32p(ws,wsoff::B2F)[0], b21 = f32p(ws,wsoff::B2F)[1];
    float* hTf = f32p(ws, wsoff::H1F0);
    const bf16* ring0 = bfp(ws, wsoff::RING0) + (size_t)rb*4*RG*256;
    bf16* ring1o       = bfp(ws, wsoff::RING1) + (size_t)(rb*2+ch)*2*RG*128;
    const bf16* ring1p = bfp(ws, wsoff::RING1) + (size_t)(rb*2+(ch^1))*2*RG*128;
    float* encp = f32p(ws,wsoff::ENCP);
    __syncthreads();
    for (int s = 0; s < 128; ++s){
      {                                   // stage h0[s] (16x256) into abuf k 0..255
        pollge(cL0, s+1);                 // h0[s] published (per-thread)
        const bf16* hs = ring0 + (size_t)(s&3)*RG*256;
        int row = tid >> 5, ck = tid & 31;
        v8s v = ldg_coh16(hs + (size_t)row*256 + ck*8);
        *(v8s*)(abuf + row*520 + ck*8) = v;
      }
      if (s >= 1 && tid < 256){           // stage partner h1 half (16x128)
        pollge(cXp, s);                   // partner finished s-1 (per-thread)
        const bf16* hp = ring1p + (size_t)((s-1)&1)*RG*128;
        int row = tid >> 4, ck = tid & 15;
        v8s v = ldg_coh16(hp + (size_t)row*128 + ck*8);
        *(v8s*)(abuf + row*520 + 256 + (ch^1)*128 + ck*8) = v;
      }
      __syncthreads();                    // S2
      v4f accr=(v4f){0,0,0,0}, accz=(v4f){0,0,0,0};
      v4f accxn=(v4f){0,0,0,0}, acchn=(v4f){0,0,0,0};
      #pragma unroll
      for (int kb=0;kb<16;kb++){
        v8s af = lds_frag8(abuf + lr*520 + kb*32 + q*8);
        #pragma unroll
        for (int g=0;g<3;g++){
          int i = g*16 + kb;
          v8s b = (i < NL1) ? ldsfrag(wlds, w*NL1 + i, lane) : wreg[i-NL1];
          v4f* A = (g==0)?&accr:(g==1)?&accz:((kb<8)?&accxn:&acchn);
          *A = mfma16(af, b, *A);
        }
      }
      int mk[4];
      #pragma unroll
      for (int rr=0;rr<4;rr++) mk[rr] = maskT[(size_t)s*NB + rowbase + q*4 + rr];
      __syncthreads();                    // S3
      bf16* slot = ring1o + (size_t)(s&1)*RG*128;
      #pragma unroll
      for (int rr=0;rr<4;rr++){
        int row = q*4 + rr;
        float rg = sigm(accr[rr] + birv);
        float zg = sigm(accz[rr] + bizv);
        float nn = tanh_f(accxn[rr] + binv + rg*(acchn[rr]+bhnv));
        float hv = (1.f-zg)*nn + zg*h1a[rr];
        float h2 = mk[rr] ? hv : h1a[rr];
        h1a[rr] = h2;
        int ch_col = w*16 + lr;
        abuf[row*520 + 256 + ch*128 + ch_col] = bf16bits(h2);
        stg_coh_pair(slot + ((size_t)row*128 + (ch_col & ~1)), lr, h2);
        if (s == 127) hTf[(size_t)(rowbase+row)*HE + d] = h2;
      }
      __syncthreads();                    // S4: h1 stores drained
      if (tid == 0) cntset(cXo, s+1);
      // ---- fused MLP (needs h1[:, :128] = ch0's own half, already in abuf) ----
      if (ch == 0 && w == 0){
        int vl = maskT[(size_t)s*NB + rowbase + lr];
        v4f acc[4];
        #pragma unroll
        for (int c=0;c<4;c++) acc[c]=(v4f){0,0,0,0};
        #pragma unroll
        for (int kb=0;kb<4;kb++){
          v8s af = vl ? lds_frag8(abuf + lr*520 + 256 + kb*32 + q*8)
                      : (v8s){0,0,0,0,0,0,0,0};
          #pragma unroll
          for (int c=0;c<4;c++) acc[c] = mfma16(af, ldsfrag(w1s, c*4+kb, lane), acc[c]);
        }
        float* outp = encp + (size_t)s*NB*2;
        #pragma unroll
        for (int rr=0;rr<4;rr++){
          float p0=0.f, p1=0.f;
          #pragma unroll
          for (int c=0;c<4;c++){
            float hv = acc[c][rr] + b1v[c]; hv = hv>0.f ? hv : 0.f;
            p0 += hv*w20[c]; p1 += hv*w21[c];
          }
          #pragma unroll
          for (int m=1;m<16;m<<=1){ p0 += __shfl_xor(p0,m,64); p1 += __shfl_xor(p1,m,64); }
          if (lr == 0){
            int grow = rowbase + q*4 + rr;
            outp[(size_t)grow*2]   = softplusf(p0+b20);
            outp[(size_t)grow*2+1] = softplusf(p1+b21);
          }
        }
      }
    }
  }
}

// ================= decoder: 5-barrier schedule (r10) + v_dot2_f32_bf16 tails =================
__global__ __attribute__((amdgpu_flat_work_group_size(512,512), amdgpu_waves_per_eu(1)))
void k_decoder(char* ws, const void* eps, const void* feat, void* out){
  extern __shared__ __align__(16) char dsm[];
  short* s_h0b = (short*)dsm;                       // [32][HDS]      @0      10496
  short* s_h1b = s_h0b + 32*HDS;                    //                @10496  10496
  float* s_inp = (float*)(dsm + 20992);             // [64]           @20992  256
  float* s_red = (float*)(dsm + 21248);             // [128]          @21248  512
  short* s_wh  = (short*)(dsm + 21760);             // WH1 t0..7 frag @21760  122880
  short* s_cw0 = (short*)(dsm + 144640);            // [3][4][132]    @144640 3168
  short* s_cwx = (short*)(dsm + 147808);            //                        3168
  short* s_cwh = (short*)(dsm + 150976);            //                        3168
  float* s_tail= (float*)(dsm + 154144);            // [512]                  2048
  float* s_th  = (float*)(dsm + 156192);            // [2][32][4]             1024
  float* s_tt0 = (float*)(dsm + 157216);            // [4][10]                160
  float* s_tt1 = (float*)(dsm + 157376);            // [4][4]                 64

  const int isbf = *(const int*)(ws+wsoff::FLAG);
  const int tid = threadIdx.x;
  const int lane = tid & 63, w = tid >> 6, lr = lane & 15, q = lane >> 4;
  const int rowbase = blockIdx.x*32;
  constexpr size_t N0v = (size_t)NS*NB*127*2;

  const bf16* W0g  = bfp(ws,wsoff::WDHH0);
  const bf16* WX1g = bfp(ws,wsoff::WDIH1);

  // ---- phase A: zero + LDS staging ----
  for (int i = tid; i < 2*32*HDS; i += 512) s_h0b[i] = 0;
  {
    const short* src = (const short*)(ws + wsoff::WDHH1);
    for (int idx = tid; idx < 120*512; idx += 512){
      int u = idx >> 9, le = idx & 511, ln = le >> 3, e = le & 7, lrr = ln & 15, qq = ln >> 4;
      int kb = u % 5, t2 = u / 5, cc = t2 & 7, g = t2 >> 3;
      s_wh[idx] = src[(size_t)(g*GDP + cc*16 + lrr)*HDP + kb*32 + qq*8 + e];
    }
    const short* g0 = (const short*)(ws + wsoff::WDHH0);
    const short* gx = (const short*)(ws + wsoff::WDIH1);
    const short* gh = (const short*)(ws + wsoff::WDHH1);
    for (int i = tid; i < 3*4*132; i += 512){
      int k = i % 132, t2 = i / 132, c4 = t2 & 3, g = t2 >> 2;
      size_t so = (size_t)(g*GDP + 128 + c4)*HDP + k;
      s_cw0[i] = g0[so]; s_cwx[i] = gx[so]; s_cwh[i] = gh[so];
    }
  }
  if (tid < 4){
    const float* wih = f32p(ws,wsoff::WDIH0F);
    const float* bi0 = f32p(ws,wsoff::BDIH0); const float* bh0 = f32p(ws,wsoff::BDHH0);
    const float* bi1 = f32p(ws,wsoff::BDIH1); const float* bh1 = f32p(ws,wsoff::BDHH1);
    int dd = 128 + tid;
    float* T = s_tt0 + tid*10;
    T[0]=wih[(0*HD+dd)*2]; T[1]=wih[(0*HD+dd)*2+1];
    T[2]=wih[(1*HD+dd)*2]; T[3]=wih[(1*HD+dd)*2+1];
    T[4]=wih[(2*HD+dd)*2]; T[5]=wih[(2*HD+dd)*2+1];
    T[6]=bi0[dd]+bh0[dd]; T[7]=bi0[HD+dd]+bh0[HD+dd]; T[8]=bi0[2*HD+dd]; T[9]=bh0[2*HD+dd];
    float* T1 = s_tt1 + tid*4;
    T1[0]=bi1[dd]+bh1[dd]; T1[1]=bi1[HD+dd]+bh1[HD+dd]; T1[2]=bi1[2*HD+dd]; T1[3]=bh1[2*HD+dd];
  }
  if (tid < 64){
    int r0 = tid >> 1, c = tid & 1;
    int b = (rowbase + r0) & 1023;
    float v = f32p(ws,wsoff::ENCP)[((size_t)127*NB + b)*2 + c];
    s_inp[tid] = v;
    st_out(out, N0v + ((size_t)(rowbase+r0)*64)*2 + c, v, isbf);
  }
  __syncthreads();

  // ---- phase B: per-thread state init + RF weights ----
  const int d = w*16 + lr;   // always < 128
  float e0a[10], e1a[4];
  {
    const float* wih = f32p(ws,wsoff::WDIH0F);
    const float* bi0 = f32p(ws,wsoff::BDIH0); const float* bh0 = f32p(ws,wsoff::BDHH0);
    const float* bi1 = f32p(ws,wsoff::BDIH1); const float* bh1 = f32p(ws,wsoff::BDHH1);
    e0a[0]=wih[(0*HD+d)*2]; e0a[1]=wih[(0*HD+d)*2+1];
    e0a[2]=wih[(1*HD+d)*2]; e0a[3]=wih[(1*HD+d)*2+1];
    e0a[4]=wih[(2*HD+d)*2]; e0a[5]=wih[(2*HD+d)*2+1];
    e0a[6]=bi0[d]+bh0[d]; e0a[7]=bi0[HD+d]+bh0[HD+d]; e0a[8]=bi0[2*HD+d]; e0a[9]=bh0[2*HD+d];
    e1a[0]=bi1[d]+bh1[d]; e1a[1]=bi1[HD+d]+bh1[HD+d]; e1a[2]=bi1[2*HD+d]; e1a[3]=bh1[2*HD+d];
  }
  float h0a[2][4], h1a[2][4];
  {
    const float* h0T = f32p(ws,wsoff::H0F0);
    const float* h1T = f32p(ws,wsoff::H1F0);
    #pragma unroll
    for (int m=0;m<2;m++)
      #pragma unroll
      for (int r=0;r<4;r++){
        int row = m*16 + q*4 + r, grow = rowbase + row;
        int s = grow >> 10, b = grow & 1023;
        float e0 = ld_any(eps, ((size_t)(s*2+0)*NB + b)*NH + d, isbf);
        float e1 = ld_any(eps, ((size_t)(s*2+1)*NB + b)*NH + d, isbf);
        float v0 = e0*__expf(0.5f*h0T[(size_t)b*HE + NH + d]) + h0T[(size_t)b*HE + d];
        float v1 = e1*__expf(0.5f*h1T[(size_t)b*HE + NH + d]) + h1T[(size_t)b*HE + d];
        h0a[m][r] = v0; h1a[m][r] = v1;
        s_h0b[row*HDS + d] = bf16bits(v0);
        s_h1b[row*HDS + d] = bf16bits(v1);
      }
  }
  if (tid < 128){
    int c4 = tid >> 5, row = tid & 31;
    int b = (rowbase + row) & 1023;
    float fc = ld_any(feat, (size_t)b*3072 + 2048 + c4, isbf);
    s_th[row*4 + c4] = fc;
    s_th[128 + row*4 + c4] = fc;
    s_h0b[row*HDS + 128 + c4] = bf16bits(fc);
    s_h1b[row*HDS + 128 + c4] = bf16bits(fc);
  }
  v8s w0f[3][5], wxf[3][5];
  #pragma unroll
  for (int g=0;g<3;g++)
    #pragma unroll
    for (int kb=0;kb<5;kb++){
      size_t off = (size_t)(g*GDP + w*16 + lr)*HDP + kb*32 + q*8;
      w0f[g][kb] = fragld(W0g, off);
      wxf[g][kb] = fragld(WX1g, off);
    }
  v8s w1f[2][4]; float b1v[2], w20v[2], w21v[2];
  if (w == 5 || w == 6){
    const int tb = (w-5)*2;
    const bf16* W1g = bfp(ws,wsoff::W1B);
    #pragma unroll
    for (int ct=0;ct<2;ct++){
      #pragma unroll
      for (int kb=0;kb<4;kb++)
        w1f[ct][kb] = fragld(W1g, (size_t)((tb+ct)*16+lr)*NH + kb*32 + q*8);
      b1v[ct]  = f32p(ws,wsoff::B1F)[(tb+ct)*16+lr];
      w20v[ct] = f32p(ws,wsoff::W2F)[(tb+ct)*16+lr];
      w21v[ct] = f32p(ws,wsoff::W2F)[64+(tb+ct)*16+lr];
    }
  }
  const float b20 = f32p(ws,wsoff::B2F)[0], b21 = f32p(ws,wsoff::B2F)[1];
  __syncthreads();

  const int ttg = tid >> 7, ttc4 = (tid >> 5) & 3, ttrow = tid & 31;
  for (int k = 0; k < 63; ++k){
    // ---- P1: main MFMA + tail dots + (k>=1: P4 combine -> s_inp, store out[k]) ----
    v4f p1[3][2];
    #pragma unroll
    for (int g=0;g<3;g++){ p1[g][0]=(v4f){0,0,0,0}; p1[g][1]=(v4f){0,0,0,0}; }
    #pragma unroll
    for (int m=0;m<2;m++)
      #pragma unroll
      for (int kb=0;kb<5;kb++){
        v8s A = lds_frag8(s_h0b + (m*16+lr)*HDS + kb*32 + q*8);
        #pragma unroll
        for (int g=0;g<3;g++) p1[g][m] = mfma16(A, w0f[g][kb], p1[g][m]);
      }
    if (k >= 1 && tid < 64){
      int row = tid >> 1, c = tid & 1;
      float p = s_red[row*2 + c] + s_red[64 + row*2 + c];
      float v = softplusf(p + (c ? b21 : b20));
      s_inp[tid] = v;
      st_out(out, N0v + ((size_t)(rowbase+row)*64 + k)*2 + c, v, isbf);
    }
    if (tid < 384){
      const unsigned* st = (const unsigned*)s_h0b + ttrow*(HDS/2);
      const unsigned* wp = (const unsigned*)s_cw0 + (ttg*4+ttc4)*66;
      float t0=0.f, t1=0.f, t2v=0.f, t3v=0.f;
      #pragma unroll 2
      for (int k2 = 0; k2 < 64; k2 += 4){
        unsigned sa=st[k2],   wa=wp[k2];
        unsigned sb=st[k2+1], wb=wp[k2+1];
        unsigned sc=st[k2+2], wc=wp[k2+2];
        unsigned sd=st[k2+3], wd=wp[k2+3];
        t0  = dot2bf(sa, wa, t0);
        t1  = dot2bf(sb, wb, t1);
        t2v = dot2bf(sc, wc, t2v);
        t3v = dot2bf(sd, wd, t3v);
      }
      { unsigned sa=st[64], wa=wp[64], sb=st[65], wb=wp[65];
        t0 = dot2bf(sa, wa, t0);
        t1 = dot2bf(sb, wb, t1); }
      s_tail[(ttg*4+ttc4)*32 + ttrow] = (t0+t1)+(t2v+t3v);
    }
    __syncthreads();
    // ---- P1 epilogue (write s_h0b new) ----
    #pragma unroll
    for (int m=0;m<2;m++)
      #pragma unroll
      for (int r=0;r<4;r++){
        int row = m*16 + q*4 + r;
        float i0 = s_inp[row*2], i1 = s_inp[row*2+1];
        float rr = sigm(i0*e0a[0]+i1*e0a[1] + p1[0][m][r] + e0a[6]);
        float zz = sigm(i0*e0a[2]+i1*e0a[3] + p1[1][m][r] + e0a[7]);
        float nn = tanh_f(i0*e0a[4]+i1*e0a[5] + e0a[8] + rr*(p1[2][m][r] + e0a[9]));
        float h = (1.f-zz)*nn + zz*h0a[m][r];
        h0a[m][r] = h;
        s_h0b[row*HDS + d] = bf16bits(h);
      }
    if (tid < 128){
      int c4 = tid >> 5, row = tid & 31;
      float ar = s_tail[(0*4+c4)*32+row], az = s_tail[(1*4+c4)*32+row], an = s_tail[(2*4+c4)*32+row];
      const float* T = s_tt0 + c4*10;
      float i0 = s_inp[row*2], i1 = s_inp[row*2+1];
      float rr = sigm(i0*T[0]+i1*T[1] + ar + T[6]);
      float zz = sigm(i0*T[2]+i1*T[3] + az + T[7]);
      float nn = tanh_f(i0*T[4]+i1*T[5] + T[8] + rr*(an + T[9]));
      float ho = s_th[row*4 + c4];
      float h = (1.f-zz)*nn + zz*ho;
      s_th[row*4 + c4] = h;
      s_h0b[row*HDS + 128 + c4] = bf16bits(h);
    }
    __syncthreads();
    // ---- P2: main MFMA + tail dots (read s_h0b new, s_h1b old) ----
    v4f p2[4][2];
    #pragma unroll
    for (int g=0;g<4;g++){ p2[g][0]=(v4f){0,0,0,0}; p2[g][1]=(v4f){0,0,0,0}; }
    #pragma unroll
    for (int m=0;m<2;m++)
      #pragma unroll
      for (int kb=0;kb<5;kb++){
        v8s ax = lds_frag8(s_h0b + (m*16+lr)*HDS + kb*32 + q*8);
        v8s ah = lds_frag8(s_h1b + (m*16+lr)*HDS + kb*32 + q*8);
        #pragma unroll
        for (int g=0;g<3;g++){
          int aix = (g==2) ? 2 : g, aih = (g==2) ? 3 : g;
          p2[aix][m] = mfma16(ax, wxf[g][kb], p2[aix][m]);
          p2[aih][m] = mfma16(ah, ldsfrag(s_wh, (g*8+w)*5 + kb, lane), p2[aih][m]);
        }
      }
    {
      const unsigned* h0p = (const unsigned*)s_h0b + ttrow*(HDS/2);
      const unsigned* h1p = (const unsigned*)s_h1b + ttrow*(HDS/2);
      float td = 0.f;
      if (ttg <= 1){
        const unsigned* wx = (const unsigned*)s_cwx + (ttg*4+ttc4)*66;
        const unsigned* wh = (const unsigned*)s_cwh + (ttg*4+ttc4)*66;
        float x0=0.f, x1=0.f, y0=0.f, y1=0.f;
        #pragma unroll 2
        for (int k2 = 0; k2 < 66; k2 += 2){
          unsigned sa=h0p[k2],   wa=wx[k2];
          unsigned sb=h0p[k2+1], wb=wx[k2+1];
          unsigned ha=h1p[k2],   va=wh[k2];
          unsigned hb=h1p[k2+1], vb=wh[k2+1];
          x0 = dot2bf(sa, wa, x0);
          x1 = dot2bf(sb, wb, x1);
          y0 = dot2bf(ha, va, y0);
          y1 = dot2bf(hb, vb, y1);
        }
        td = (x0+x1)+(y0+y1);
      } else if (ttg == 2){
        const unsigned* wx = (const unsigned*)s_cwx + (2*4+ttc4)*66;
        float x0=0.f, x1=0.f;
        #pragma unroll 2
        for (int k2 = 0; k2 < 66; k2 += 2){
          unsigned sa=h0p[k2], wa=wx[k2], sb=h0p[k2+1], wb=wx[k2+1];
          x0 = dot2bf(sa, wa, x0);
          x1 = dot2bf(sb, wb, x1);
        }
        td = x0+x1;
      } else {
        const unsigned* wh = (const unsigned*)s_cwh + (2*4+ttc4)*66;
        float y0=0.f, y1=0.f;
        #pragma unroll 2
        for (int k2 = 0; k2 < 66; k2 += 2){
          unsigned sa=h1p[k2], wa=wh[k2], sb=h1p[k2+1], wb=wh[k2+1];
          y0 = dot2bf(sa, wa, y0);
          y1 = dot2bf(sb, wb, y1);
        }
        td = y0+y1;
      }
      s_tail[(ttg*4+ttc4)*32 + ttrow] = td;
    }
    __syncthreads();
    // ---- P2 epilogue (write s_h1b new) ----
    #pragma unroll
    for (int m=0;m<2;m++)
      #pragma unroll
      for (int r=0;r<4;r++){
        int row = m*16 + q*4 + r;
        float rr = sigm(p2[0][m][r] + e1a[0]);
        float zz = sigm(p2[1][m][r] + e1a[1]);
        float nn = tanh_f(p2[2][m][r] + e1a[2] + rr*(p2[3][m][r] + e1a[3]));
        float h = (1.f-zz)*nn + zz*h1a[m][r];
        h1a[m][r] = h;
        s_h1b[row*HDS + d] = bf16bits(h);
      }
    if (tid < 128){
      int c4 = tid >> 5, row = tid & 31;
      float tr = s_tail[(0*4+c4)*32+row], tz = s_tail[(1*4+c4)*32+row];
      float txn = s_tail[(2*4+c4)*32+row], thn = s_tail[(3*4+c4)*32+row];
      const float* T1 = s_tt1 + c4*4;
      float rr = sigm(tr + T1[0]);
      float zz = sigm(tz + T1[1]);
      float nn = tanh_f(txn + T1[2] + rr*(thn + T1[3]));
      float ho = s_th[128 + row*4 + c4];
      float h = (1.f-zz)*nn + zz*ho;
      s_th[128 + row*4 + c4] = h;
      s_h1b[row*HDS + 128 + c4] = bf16bits(h);
    }
    __syncthreads();
    // ---- P3: MLP halves on waves 5,6 ----
    if (w == 5 || w == 6){
      v4f a3[2][2];
      #pragma unroll
      for (int ct=0;ct<2;ct++){ a3[ct][0]=(v4f){0,0,0,0}; a3[ct][1]=(v4f){0,0,0,0}; }
      #pragma unroll
      for (int m=0;m<2;m++)
        #pragma unroll
        for (int kb=0;kb<4;kb++){
          v8s A = lds_frag8(s_h1b + (m*16+lr)*HDS + kb*32 + q*8);
          #pragma unroll
          for (int ct=0;ct<2;ct++) a3[ct][m] = mfma16(A, w1f[ct][kb], a3[ct][m]);
        }
      #pragma unroll
      for (int m=0;m<2;m++)
        #pragma unroll
        for (int r=0;r<4;r++){
          float p0 = 0.f, p1v = 0.f;
          #pragma unroll
          for (int ct=0;ct<2;ct++){
            float hv = a3[ct][m][r] + b1v[ct]; hv = hv > 0.f ? hv : 0.f;
            p0 += hv*w20v[ct]; p1v += hv*w21v[ct];
          }
          #pragma unroll
          for (int mm=1;mm<16;mm<<=1){ p0 += __shfl_xor(p0,mm,64); p1v += __shfl_xor(p1v,mm,64); }
          if (lr == 0){
            int row = m*16 + q*4 + r;
            s_red[(w-5)*64 + row*2]   = p0;
            s_red[(w-5)*64 + row*2+1] = p1v;
          }
        }
    }
    __syncthreads();
  }
  // ---- final combine: out[63] (uses s_red from last P3) ----
  if (tid < 64){
    int row = tid >> 1, c = tid & 1;
    float p = s_red[row*2 + c] + s_red[64 + row*2 + c];
    float v = softplusf(p + (c ? b21 : b20));
    st_out(out, N0v + ((size_t)(rowbase+row)*64 + 63)*2 + c, v, isbf);
  }
}

// ---------- encoder-part output assembly ----------
__global__ void k_assemble_enc(char* ws, void* out){
  int isbf = *(const int*)(ws+wsoff::FLAG);
  const float* encp = f32p(ws,wsoff::ENCP);
  constexpr size_t N0v = (size_t)NS*NB*127*2;
  for (size_t i = (size_t)blockIdx.x*blockDim.x + threadIdx.x; i < N0v;
       i += (size_t)gridDim.x*blockDim.x){
    int c = (int)(i & 1); size_t qq = i >> 1;
    int tt = (int)(qq % 127); size_t q2 = qq / 127; int b = (int)(q2 & 1023);
    st_out(out, i, encp[((size_t)tt*NB + b)*2 + c], isbf);
  }
}

extern "C" void kernel_launch(void* const* d_in, const int* in_sizes, int n_in,
                              void* d_out, int out_size, void* d_ws, size_t ws_size,
                              hipStream_t stream) {
  char* ws = (char*)d_ws;
  const int* mask = (const int*)d_in[2];
  auto gb = [](size_t n){ return dim3((unsigned)((n + 255)/256)); };

  hipMemsetAsync(ws+wsoff::CNT, 0, 192*64, stream);

  k_detect<<<1,64,0,stream>>>(ws, d_in[3]);

  k_stage_xs   <<<gb((size_t)NT*NB*KX),256,0,stream>>>(ws, d_in[0], d_in[1]);
  k_stage_maskT<<<gb((size_t)NT*NB),256,0,stream>>>(ws, mask);
  k_stage_pad<<<gb(768*32) ,256,0,stream>>>(ws, d_in[7],  wsoff::WIH0, 768, 18, 32);
  k_stage_pad<<<gb(768*256),256,0,stream>>>(ws, d_in[8],  wsoff::WHH0, 768, 256, 256);
  k_stage_pad<<<gb(768*256),256,0,stream>>>(ws, d_in[11], wsoff::WIH1, 768, 256, 256);
  k_stage_pad<<<gb(768*256),256,0,stream>>>(ws, d_in[12], wsoff::WHH1, 768, 256, 256);
  k_stage_pad<<<gb(64*128) ,256,0,stream>>>(ws, d_in[23], wsoff::W1B,  64, 128, 128);
  k_stage_dec<<<gb(432*HDP),256,0,stream>>>(ws, d_in[16], wsoff::WDHH0);
  k_stage_dec<<<gb(432*HDP),256,0,stream>>>(ws, d_in[19], wsoff::WDIH1);
  k_stage_dec<<<gb(432*HDP),256,0,stream>>>(ws, d_in[20], wsoff::WDHH1);

  SmallSegs ss;
  const void* srcs[12] = {d_in[9],d_in[10],d_in[13],d_in[14],d_in[15],
                          d_in[17],d_in[18],d_in[21],d_in[22],
                          d_in[24],d_in[25],d_in[26]};
  const size_t offs[12] = {wsoff::BIH0,wsoff::BHH0,wsoff::BIH1,wsoff::BHH1,wsoff::WDIH0F,
                           wsoff::BDIH0,wsoff::BDHH0,wsoff::BDIH1,wsoff::BDHH1,
                           wsoff::B1F,wsoff::W2F,wsoff::B2F};
  const int ns[12] = {768,768,768,768,792,396,396,396,396,64,128,2};
  for (int i=0;i<12;i++){ ss.src[i]=srcs[i]; ss.dstoff[i]=(int)offs[i]; ss.n[i]=ns[i]; }
  k_stage_small<<<12,256,0,stream>>>(ws, ss);

  hipFuncSetAttribute(reinterpret_cast<const void*>(k_encoder),
                      hipFuncAttributeMaxDynamicSharedMemorySize, ENC_LDS);
  hipFuncSetAttribute(reinterpret_cast<const void*>(k_decoder),
                      hipFuncAttributeMaxDynamicSharedMemorySize, 157440);

  k_encoder<<<192,512,ENC_LDS,stream>>>(ws);
  k_decoder<<<256,512,157440,stream>>>(ws, d_in[3], d_in[1], d_out);
  k_assemble_enc<<<2048,256,0,stream>>>(ws, d_out);
}